// Round 2
// baseline (5282.316 us; speedup 1.0000x reference)
//
#include <hip/hip_runtime.h>
#include <cstdint>
#include <cstddef>

#define NN   256      // nodes
#define HIDD 128      // hidden
#define NB   32       // graphs per batch
#define TT   16       // timesteps
#define BSZ  (NB*NN)  // 8192 rows

struct GP {
  const float* W[8];  // s=0..3: Wi,Wf,Wc,Wo ; s=4..7: Ui,Uf,Uc,Uo
  const float* A[8];  // matching a-vectors (256,)
};

// ---------------- K1: hW[s] = src_s @ W_s  (f32) ----------------
__global__ __launch_bounds__(256) void k1_gemm(const float* __restrict__ x,
    const float* __restrict__ hstate, GP gp, float* __restrict__ hW, int t)
{
  const int s = blockIdx.y;
  const int row0 = blockIdx.x * 32;
  const int tid = threadIdx.x;
  __shared__ float srcL[32*HIDD];
  const float* __restrict__ W = gp.W[s];
  if (s < 4) {
    #pragma unroll
    for (int i = 0; i < 16; ++i) {
      int idx = tid + i*256;
      int r = idx >> 7, k = idx & 127;
      srcL[idx] = x[(size_t)(row0 + r)*(TT*HIDD) + (size_t)t*HIDD + k];
    }
  } else {
    #pragma unroll
    for (int i = 0; i < 16; ++i) {
      int idx = tid + i*256;
      srcL[idx] = hstate[(size_t)row0*HIDD + idx];
    }
  }
  __syncthreads();
  const int c2 = tid & 63;   // column pair: cols 2*c2, 2*c2+1
  const int r8 = tid >> 6;   // row group: rows r8*8 .. +7
  float acc[8][2];
  #pragma unroll
  for (int rr = 0; rr < 8; ++rr) { acc[rr][0] = 0.f; acc[rr][1] = 0.f; }
  const float2* __restrict__ W2 = reinterpret_cast<const float2*>(W);
  const float4* s4 = reinterpret_cast<const float4*>(srcL);
  for (int k4 = 0; k4 < 32; ++k4) {
    float2 w0 = W2[(k4*4+0)*64 + c2];
    float2 w1 = W2[(k4*4+1)*64 + c2];
    float2 w2 = W2[(k4*4+2)*64 + c2];
    float2 w3 = W2[(k4*4+3)*64 + c2];
    #pragma unroll
    for (int rr = 0; rr < 8; ++rr) {
      float4 sv = s4[(r8*8+rr)*32 + k4];
      acc[rr][0] += sv.x*w0.x + sv.y*w1.x + sv.z*w2.x + sv.w*w3.x;
      acc[rr][1] += sv.x*w0.y + sv.y*w1.y + sv.z*w2.y + sv.w*w3.y;
    }
  }
  float2* __restrict__ o2 = reinterpret_cast<float2*>(hW);
  #pragma unroll
  for (int rr = 0; rr < 8; ++rr) {
    int row = row0 + r8*8 + rr;
    o2[((size_t)s*BSZ + row)*64 + c2] = make_float2(acc[rr][0], acc[rr][1]);
  }
}

// ---------------- K2: gat[s] = elu(softmax(leaky(f1_i+f2_j)) @ hW), all f32 ----------------
__global__ __launch_bounds__(256) void k2_attn(const float* __restrict__ hW,
    GP gp, float* __restrict__ gat)
{
  const int s = blockIdx.y;
  const int b = blockIdx.x;
  const int tid = threadIdx.x, lane = tid & 63, w = tid >> 6;
  __shared__ float hU[NN*HIDD];               // 128 KB f32 h-tile
  float* fL = hU;                             // transient alias for f1/f2 (1 KB each)
  const float* __restrict__ a1 = gp.A[s];
  const float* __restrict__ a2 = a1 + HIDD;
  const float* __restrict__ hWb = hW + ((size_t)s*BSZ + (size_t)b*NN)*HIDD;

  // phase 0: f1/f2 per node (f32)
  {
    const float4* r4  = reinterpret_cast<const float4*>(hWb + (size_t)tid*HIDD);
    const float4* A14 = reinterpret_cast<const float4*>(a1);
    const float4* A24 = reinterpret_cast<const float4*>(a2);
    float d1 = 0.f, d2 = 0.f;
    #pragma unroll 4
    for (int k4 = 0; k4 < 32; ++k4) {
      float4 v = r4[k4];
      float4 u = A14[k4], q = A24[k4];
      d1 += v.x*u.x + v.y*u.y + v.z*u.z + v.w*u.w;
      d2 += v.x*q.x + v.y*q.y + v.z*q.z + v.w*q.w;
    }
    fL[tid] = d1;
    fL[256 + tid] = d2;
  }
  __syncthreads();
  float f1r[4], f2r[4];
  #pragma unroll
  for (int c = 0; c < 4; ++c) {
    f1r[c] = fL[c*64 + lane];
    f2r[c] = fL[256 + c*64 + lane];
  }
  __syncthreads();
  // phase 1: stage full f32 h-tile (overwrites fL region)
  {
    float4* hU4 = reinterpret_cast<float4*>(hU);
    const float4* s4 = reinterpret_cast<const float4*>(hWb);
    #pragma unroll
    for (int i = 0; i < 32; ++i) {
      int idx = tid + i*256;
      hU4[idx] = s4[idx];
    }
  }
  __syncthreads();

  const int base = w*64;                  // this wave's 64 rows
  const float f1src = f1r[w];
  float* __restrict__ gout = gat + ((size_t)s*BSZ + (size_t)b*NN)*HIDD;
  const float2* hU2 = reinterpret_cast<const float2*>(hU);

  for (int pp = 0; pp < 16; ++pp) {       // 4 rows per iteration
    const int i0 = base + 4*pp;
    float f1v[4];
    #pragma unroll
    for (int r = 0; r < 4; ++r) f1v[r] = __shfl(f1src, 4*pp + r, 64);

    float p[4][4], m[4], sum[4];
    #pragma unroll
    for (int r = 0; r < 4; ++r) {
      m[r] = -1e30f;
      #pragma unroll
      for (int c = 0; c < 4; ++c) {
        float e = f1v[r] + f2r[c];
        e = e > 0.f ? e : 0.01f*e;
        p[r][c] = e;
        m[r] = fmaxf(m[r], e);
      }
    }
    #pragma unroll
    for (int r = 0; r < 4; ++r) {
      #pragma unroll
      for (int off = 32; off > 0; off >>= 1)
        m[r] = fmaxf(m[r], __shfl_xor(m[r], off, 64));
    }
    #pragma unroll
    for (int r = 0; r < 4; ++r) {
      sum[r] = 0.f;
      #pragma unroll
      for (int c = 0; c < 4; ++c) { p[r][c] = expf(p[r][c] - m[r]); sum[r] += p[r][c]; }
    }
    #pragma unroll
    for (int r = 0; r < 4; ++r) {
      #pragma unroll
      for (int off = 32; off > 0; off >>= 1)
        sum[r] += __shfl_xor(sum[r], off, 64);
    }
    #pragma unroll
    for (int r = 0; r < 4; ++r) {
      float rs = 1.f / sum[r];
      #pragma unroll
      for (int c = 0; c < 4; ++c) p[r][c] *= rs;
    }

    float acc[4][2];
    #pragma unroll
    for (int r = 0; r < 4; ++r) { acc[r][0] = 0.f; acc[r][1] = 0.f; }
    #pragma unroll
    for (int c = 0; c < 4; ++c) {
      #pragma unroll 4
      for (int l = 0; l < 64; ++l) {
        float2 hv = hU2[(c*64 + l)*64 + lane];
        #pragma unroll
        for (int r = 0; r < 4; ++r) {
          float pv = __shfl(p[r][c], l, 64);
          acc[r][0] += pv*hv.x;
          acc[r][1] += pv*hv.y;
        }
      }
    }
    #pragma unroll
    for (int r = 0; r < 4; ++r) {
      float o0 = acc[r][0] > 0.f ? acc[r][0] : expm1f(acc[r][0]);
      float o1 = acc[r][1] > 0.f ? acc[r][1] : expm1f(acc[r][1]);
      reinterpret_cast<float2*>(gout)[(size_t)(i0+r)*64 + lane] = make_float2(o0, o1);
    }
  }
}

// ---------------- K3: LSTM gate combine ----------------
__global__ __launch_bounds__(256) void k3_gates(const float* __restrict__ gat,
    const float* __restrict__ bi, const float* __restrict__ bfv,
    const float* __restrict__ bc, const float* __restrict__ bo,
    float* __restrict__ cstate, float* __restrict__ hmid)
{
  size_t idx = (size_t)blockIdx.x*256 + threadIdx.x;
  int hc = (int)(idx & 127);
  const size_t S = (size_t)BSZ*HIDD;
  float gi = gat[idx]       + gat[4*S+idx] + bi[hc];
  float gf = gat[S+idx]     + gat[5*S+idx] + bfv[hc];
  float gc = gat[2*S+idx]   + gat[6*S+idx] + bc[hc];
  float go = gat[3*S+idx]   + gat[7*S+idx] + bo[hc];
  float it = 1.f/(1.f+expf(-gi));
  float ft = 1.f/(1.f+expf(-gf));
  float gt = tanhf(gc);
  float ot = 1.f/(1.f+expf(-go));
  float c = ft*cstate[idx] + it*gt;
  cstate[idx] = c;
  hmid[idx] = ot*tanhf(c);
}

// ---------------- K4: node pool -> q -> qq = q@linq^T + linq_b + linh_b ----------------
__global__ __launch_bounds__(128) void k4_pool(const float* __restrict__ hmid,
    const float* __restrict__ pw, const float* __restrict__ pb,
    const float* __restrict__ lqw, const float* __restrict__ lqb,
    const float* __restrict__ lhb, float* __restrict__ qq)
{
  int b = blockIdx.x, h = threadIdx.x;
  float q = 0.f;
  for (int n = 0; n < NN; ++n)
    q += hmid[((size_t)b*NN + n)*HIDD + h] * pw[n];
  q += pb[0];
  q = fmaxf(q, 0.f);
  __shared__ float qL[HIDD];
  qL[h] = q;
  __syncthreads();
  float acc = 0.f;
  #pragma unroll 4
  for (int k = 0; k < HIDD; ++k) acc += qL[k]*lqw[h*HIDD + k];
  qq[b*HIDD + h] = acc + lqb[h] + lhb[h];
}

// ---------------- K5: t=tanh(h@linh^T+qq); a=sigmoid(t@linu^T+b); h*(1+a), all f32 ----------------
__global__ __launch_bounds__(256) void k5_fatt(const float* __restrict__ hmid,
    const float* __restrict__ lhw, const float* __restrict__ luw,
    const float* __restrict__ lub, const float* __restrict__ qq,
    float* __restrict__ hstate)
{
  const int tid = threadIdx.x, lane = tid & 63, w = tid >> 6;
  const int row0 = blockIdx.x * 32;
  const int b = row0 >> 8;                  // 32 rows never cross a batch
  __shared__ float lhT[HIDD*130];           // linh^T, f32, padded stride 130
  __shared__ float rows[4][HIDD];
  #pragma unroll
  for (int i = 0; i < 64; ++i) {
    int idx = tid + i*256;
    int hp = idx >> 7, k = idx & 127;
    lhT[k*130 + hp] = lhw[idx];
  }
  float q0 = qq[b*HIDD + 2*lane];
  float q1 = qq[b*HIDD + 2*lane + 1];
  float lu0 = luw[2*lane], lu1 = luw[2*lane+1];
  float lb = lub[0];
  __syncthreads();
  for (int chunk = 0; chunk < 8; ++chunk) {
    int r0 = row0 + chunk*4;
    #pragma unroll
    for (int i = 0; i < 2; ++i) {
      int idx = tid + i*256;
      rows[idx >> 7][idx & 127] = hmid[(size_t)r0*HIDD + idx];
    }
    __syncthreads();
    const float* R = rows[w];
    float d0 = 0.f, d1 = 0.f;
    #pragma unroll 4
    for (int k = 0; k < HIDD; ++k) {
      float2 lv = *reinterpret_cast<const float2*>(&lhT[k*130 + 2*lane]);
      float rv = R[k];
      d0 += rv*lv.x;
      d1 += rv*lv.y;
    }
    float t0 = tanhf(d0 + q0);
    float t1 = tanhf(d1 + q1);
    float ap = t0*lu0 + t1*lu1;
    #pragma unroll
    for (int off = 32; off > 0; off >>= 1) ap += __shfl_xor(ap, off, 64);
    float a = 1.f/(1.f+expf(-(ap + lb)));
    float o0 = R[2*lane]  *(1.f+a);
    float o1 = R[2*lane+1]*(1.f+a);
    reinterpret_cast<float2*>(hstate)[(size_t)(r0+w)*64 + lane] = make_float2(o0, o1);
    __syncthreads();
  }
}

// ---------------- K6: transposed write of hidden_seq ----------------
__global__ __launch_bounds__(256) void k6_tr(const float* __restrict__ hstate,
    float* __restrict__ out, int t)
{
  __shared__ float tile[128*65];
  const int r0 = blockIdx.x * 64;
  const int tid = threadIdx.x;
  #pragma unroll
  for (int i = 0; i < 32; ++i) {
    int idx = tid + i*256;
    int r = idx >> 7, h = idx & 127;
    tile[h*65 + r] = hstate[(size_t)(r0 + r)*HIDD + h];
  }
  __syncthreads();
  #pragma unroll
  for (int i = 0; i < 32; ++i) {
    int idx = tid + i*256;
    int h = idx >> 6, rr = idx & 63;
    out[(size_t)h*(TT*(size_t)BSZ) + (size_t)t*BSZ + r0 + rr] = tile[h*65 + rr];
  }
}

// ---------------- K7: append (h_T, c_T) ----------------
__global__ __launch_bounds__(256) void k7_final(const float* __restrict__ hstate,
    const float* __restrict__ cstate, float* __restrict__ out)
{
  size_t idx = (size_t)blockIdx.x*256 + threadIdx.x;
  const size_t off = (size_t)HIDD * (size_t)TT * (size_t)BSZ;  // 16777216
  out[off + idx] = hstate[idx];
  out[off + (size_t)BSZ*HIDD + idx] = cstate[idx];
}

extern "C" void kernel_launch(void* const* d_in, const int* in_sizes, int n_in,
                              void* d_out, int out_size, void* d_ws, size_t ws_size,
                              hipStream_t stream)
{
  const float* x = (const float*)d_in[0];
  GP gp;
  int wIdx[8], aIdx[8], bIdx[4];
  // setup_inputs() dict order interleaves b_g per gate group:
  //   x, [Wg_W, Wg_a, Ug_W, Ug_a, b_g] x {i,f,c,o}, pool_w, ...
  // Detect at runtime: in dict order, index 5 is b_i (128 elems);
  // in reference-signature order, index 5 is Wf_W (16384 elems).
  bool dictOrder = (in_sizes[5] == HIDD);
  if (dictOrder) {
    for (int g = 0; g < 4; ++g) {
      int base = 1 + 5*g;
      wIdx[g]   = base;     aIdx[g]   = base + 1;   // W-side GAT
      wIdx[4+g] = base + 2; aIdx[4+g] = base + 3;   // U-side GAT
      bIdx[g]   = base + 4;
    }
  } else {
    for (int g = 0; g < 4; ++g) {
      int base = 1 + 4*g;
      wIdx[g]   = base;     aIdx[g]   = base + 1;
      wIdx[4+g] = base + 2; aIdx[4+g] = base + 3;
      bIdx[g]   = 17 + g;
    }
  }
  for (int s = 0; s < 8; ++s) {
    gp.W[s] = (const float*)d_in[wIdx[s]];
    gp.A[s] = (const float*)d_in[aIdx[s]];
  }
  const float* bi  = (const float*)d_in[bIdx[0]];
  const float* bf  = (const float*)d_in[bIdx[1]];
  const float* bc  = (const float*)d_in[bIdx[2]];
  const float* bo  = (const float*)d_in[bIdx[3]];
  const float* pw  = (const float*)d_in[21];
  const float* pb  = (const float*)d_in[22];
  const float* lhw = (const float*)d_in[23];
  const float* lhb = (const float*)d_in[24];
  const float* lqw = (const float*)d_in[25];
  const float* lqb = (const float*)d_in[26];
  const float* luw = (const float*)d_in[27];
  const float* lub = (const float*)d_in[28];

  // workspace layout (floats): total ~19.93M floats (~79.7 MB)
  float* ws = (float*)d_ws;
  const size_t S = (size_t)BSZ*HIDD;       // 1048576
  float* hW     = ws;                      // 8*S
  float* gat    = hW + 8*S;                // 8*S
  float* hstate = gat + 8*S;               // S
  float* cstate = hstate + S;              // S
  float* hmid   = cstate + S;              // S
  float* qq     = hmid + S;                // NB*HIDD
  float* out = (float*)d_out;

  hipMemsetAsync(hstate, 0, S*sizeof(float), stream);
  hipMemsetAsync(cstate, 0, S*sizeof(float), stream);

  for (int t = 0; t < TT; ++t) {
    k1_gemm<<<dim3(256, 8), 256, 0, stream>>>(x, hstate, gp, hW, t);
    k2_attn<<<dim3(NB, 8), 256, 0, stream>>>(hW, gp, gat);
    k3_gates<<<4096, 256, 0, stream>>>(gat, bi, bf, bc, bo, cstate, hmid);
    k4_pool<<<NB, 128, 0, stream>>>(hmid, pw, pb, lqw, lqb, lhb, qq);
    k5_fatt<<<256, 256, 0, stream>>>(hmid, lhw, luw, lub, qq, hstate);
    k6_tr<<<128, 256, 0, stream>>>(hstate, out, t);
  }
  k7_final<<<4096, 256, 0, stream>>>(hstate, cstate, out);
}

// Round 3
// 2480.646 us; speedup vs baseline: 2.1294x; 2.1294x over previous
//
#include <hip/hip_runtime.h>
#include <cstdint>
#include <cstddef>

#define NN   256      // nodes
#define HIDD 128      // hidden
#define NB   32       // graphs per batch
#define TT   16       // timesteps
#define BSZ  (NB*NN)  // 8192 rows

struct GP {
  const float* W[8];  // s=0..3: Wi,Wf,Wc,Wo ; s=4..7: Ui,Uf,Uc,Uo
  const float* A[8];  // matching a-vectors (256,)
};

typedef __attribute__((ext_vector_type(8))) short bf16x8;
typedef __attribute__((ext_vector_type(4))) float f32x4;

__device__ __forceinline__ uint16_t bf16rn(float f) {
  uint32_t u = __float_as_uint(f);
  uint32_t r = u + 0x7fffu + ((u >> 16) & 1u);
  return (uint16_t)(r >> 16);
}
__device__ __forceinline__ float bf16f(uint16_t h) {
  return __uint_as_float((uint32_t)h << 16);
}

// ---------------- K1: hW[s] = src_s @ W_s  (f32) ----------------
__global__ __launch_bounds__(256) void k1_gemm(const float* __restrict__ x,
    const float* __restrict__ hstate, GP gp, float* __restrict__ hW, int t)
{
  const int s = blockIdx.y;
  const int row0 = blockIdx.x * 32;
  const int tid = threadIdx.x;
  __shared__ float srcL[32*HIDD];
  const float* __restrict__ W = gp.W[s];
  if (s < 4) {
    #pragma unroll
    for (int i = 0; i < 16; ++i) {
      int idx = tid + i*256;
      int r = idx >> 7, k = idx & 127;
      srcL[idx] = x[(size_t)(row0 + r)*(TT*HIDD) + (size_t)t*HIDD + k];
    }
  } else {
    #pragma unroll
    for (int i = 0; i < 16; ++i) {
      int idx = tid + i*256;
      srcL[idx] = hstate[(size_t)row0*HIDD + idx];
    }
  }
  __syncthreads();
  const int c2 = tid & 63;   // column pair: cols 2*c2, 2*c2+1
  const int r8 = tid >> 6;   // row group: rows r8*8 .. +7
  float acc[8][2];
  #pragma unroll
  for (int rr = 0; rr < 8; ++rr) { acc[rr][0] = 0.f; acc[rr][1] = 0.f; }
  const float2* __restrict__ W2 = reinterpret_cast<const float2*>(W);
  const float4* s4 = reinterpret_cast<const float4*>(srcL);
  for (int k4 = 0; k4 < 32; ++k4) {
    float2 w0 = W2[(k4*4+0)*64 + c2];
    float2 w1 = W2[(k4*4+1)*64 + c2];
    float2 w2 = W2[(k4*4+2)*64 + c2];
    float2 w3 = W2[(k4*4+3)*64 + c2];
    #pragma unroll
    for (int rr = 0; rr < 8; ++rr) {
      float4 sv = s4[(r8*8+rr)*32 + k4];
      acc[rr][0] += sv.x*w0.x + sv.y*w1.x + sv.z*w2.x + sv.w*w3.x;
      acc[rr][1] += sv.x*w0.y + sv.y*w1.y + sv.z*w2.y + sv.w*w3.y;
    }
  }
  float2* __restrict__ o2 = reinterpret_cast<float2*>(hW);
  #pragma unroll
  for (int rr = 0; rr < 8; ++rr) {
    int row = row0 + r8*8 + rr;
    o2[((size_t)s*BSZ + row)*64 + c2] = make_float2(acc[rr][0], acc[rr][1]);
  }
}

// ---------------- K2: gat[s] = elu(softmax(leaky(f1_i+f2_j)) @ hW) ----------------
// MFMA version: softmax stats in f32 per lane-owned row; PV via
// mfma_f32_16x16x32_bf16 with P single-bf16 and H split hi/lo bf16.
__global__ __launch_bounds__(256) void k2_attn(const float* __restrict__ hW,
    GP gp, float* __restrict__ gat)
{
  const int s = blockIdx.y;
  const int b = blockIdx.x;
  const int tid = threadIdx.x, lane = tid & 63, w = tid >> 6;
  __shared__ __align__(16) float f1L[NN];
  __shared__ __align__(16) float f2L[NN];
  __shared__ __align__(16) uint16_t Pb[NN*64];    // 32 KB  [row][64k] swizzled
  __shared__ __align__(16) uint16_t Hh[HIDD*64];  // 16 KB  [col][64k] hi, swizzled
  __shared__ __align__(16) uint16_t Hl[HIDD*64];  // 16 KB  lo
  const float* __restrict__ a1 = gp.A[s];
  const float* __restrict__ a2 = a1 + HIDD;
  const float* __restrict__ hWb = hW + ((size_t)s*BSZ + (size_t)b*NN)*HIDD;

  // phase 0: f1/f2 per node (f32); thread -> row tid
  {
    const float4* r4  = reinterpret_cast<const float4*>(hWb + (size_t)tid*HIDD);
    const float4* A14 = reinterpret_cast<const float4*>(a1);
    const float4* A24 = reinterpret_cast<const float4*>(a2);
    float d1 = 0.f, d2 = 0.f;
    #pragma unroll 4
    for (int k4 = 0; k4 < 32; ++k4) {
      float4 v = r4[k4];
      float4 u = A14[k4], q = A24[k4];
      d1 += v.x*u.x + v.y*u.y + v.z*u.z + v.w*u.w;
      d2 += v.x*q.x + v.y*q.y + v.z*q.z + v.w*q.w;
    }
    f1L[tid] = d1;
    f2L[tid] = d2;
  }
  __syncthreads();

  // phase 1: softmax stats for row = tid (f2 reads are wave-broadcast)
  const float4* f24 = reinterpret_cast<const float4*>(f2L);
  float f1v = f1L[tid];
  float m = -1e30f;
  #pragma unroll 8
  for (int j4 = 0; j4 < 64; ++j4) {
    float4 v = f24[j4];
    float e0 = f1v + v.x; e0 = e0 > 0.f ? e0 : 0.01f*e0;
    float e1 = f1v + v.y; e1 = e1 > 0.f ? e1 : 0.01f*e1;
    float e2 = f1v + v.z; e2 = e2 > 0.f ? e2 : 0.01f*e2;
    float e3 = f1v + v.w; e3 = e3 > 0.f ? e3 : 0.01f*e3;
    m = fmaxf(m, fmaxf(fmaxf(e0, e1), fmaxf(e2, e3)));
  }
  float ssum = 0.f;
  #pragma unroll 8
  for (int j4 = 0; j4 < 64; ++j4) {
    float4 v = f24[j4];
    float e0 = f1v + v.x; e0 = e0 > 0.f ? e0 : 0.01f*e0;
    float e1 = f1v + v.y; e1 = e1 > 0.f ? e1 : 0.01f*e1;
    float e2 = f1v + v.z; e2 = e2 > 0.f ? e2 : 0.01f*e2;
    float e3 = f1v + v.w; e3 = e3 > 0.f ? e3 : 0.01f*e3;
    ssum += expf(e0 - m) + expf(e1 - m) + expf(e2 - m) + expf(e3 - m);
  }
  float rs = 1.f / ssum;

  f32x4 acc[4][8];
  #pragma unroll
  for (int r = 0; r < 4; ++r)
    #pragma unroll
    for (int c = 0; c < 8; ++c)
      acc[r][c] = (f32x4){0.f, 0.f, 0.f, 0.f};

  char* PbB = reinterpret_cast<char*>(Pb);
  char* HhB = reinterpret_cast<char*>(Hh);
  char* HlB = reinterpret_cast<char*>(Hl);
  const int kg = lane >> 4;

  for (int kc = 0; kc < 4; ++kc) {
    __syncthreads();   // previous chunk's MFMA reads done
    // stage H chunk [col][64k] split hi/lo, 16B-block XOR swizzle by (col&7)
    #pragma unroll 4
    for (int it = 0; it < 16; ++it) {
      int idx = it*256 + tid;
      int c = idx & 127, kp = idx >> 7;      // kp in 0..31 (u32 = k-pair)
      float v0 = hWb[(size_t)(kc*64 + 2*kp)  *HIDD + c];
      float v1 = hWb[(size_t)(kc*64 + 2*kp+1)*HIDD + c];
      uint16_t h0 = bf16rn(v0), h1 = bf16rn(v1);
      uint16_t l0 = bf16rn(v0 - bf16f(h0)), l1 = bf16rn(v1 - bf16f(h1));
      int off = c*128 + ((((kp>>2) ^ (c & 7)) << 4) | ((kp & 3) << 2));
      *reinterpret_cast<uint32_t*>(HhB + off) = (uint32_t)h0 | ((uint32_t)h1 << 16);
      *reinterpret_cast<uint32_t*>(HlB + off) = (uint32_t)l0 | ((uint32_t)l1 << 16);
    }
    // P-gen for row = tid: 64 probs -> bf16 -> swizzled b128 writes
    #pragma unroll
    for (int blk = 0; blk < 8; ++blk) {
      float4 va = f24[kc*16 + blk*2];
      float4 vb = f24[kc*16 + blk*2 + 1];
      float e0 = f1v + va.x; e0 = e0 > 0.f ? e0 : 0.01f*e0;
      float e1 = f1v + va.y; e1 = e1 > 0.f ? e1 : 0.01f*e1;
      float e2 = f1v + va.z; e2 = e2 > 0.f ? e2 : 0.01f*e2;
      float e3 = f1v + va.w; e3 = e3 > 0.f ? e3 : 0.01f*e3;
      float e4 = f1v + vb.x; e4 = e4 > 0.f ? e4 : 0.01f*e4;
      float e5 = f1v + vb.y; e5 = e5 > 0.f ? e5 : 0.01f*e5;
      float e6 = f1v + vb.z; e6 = e6 > 0.f ? e6 : 0.01f*e6;
      float e7 = f1v + vb.w; e7 = e7 > 0.f ? e7 : 0.01f*e7;
      float p0 = expf(e0 - m)*rs, p1 = expf(e1 - m)*rs;
      float p2 = expf(e2 - m)*rs, p3 = expf(e3 - m)*rs;
      float p4 = expf(e4 - m)*rs, p5 = expf(e5 - m)*rs;
      float p6 = expf(e6 - m)*rs, p7 = expf(e7 - m)*rs;
      uint32_t u0 = (uint32_t)bf16rn(p0) | ((uint32_t)bf16rn(p1) << 16);
      uint32_t u1 = (uint32_t)bf16rn(p2) | ((uint32_t)bf16rn(p3) << 16);
      uint32_t u2 = (uint32_t)bf16rn(p4) | ((uint32_t)bf16rn(p5) << 16);
      uint32_t u3 = (uint32_t)bf16rn(p6) | ((uint32_t)bf16rn(p7) << 16);
      *reinterpret_cast<uint4*>(PbB + tid*128 + ((blk ^ (tid & 7)) << 4)) =
          make_uint4(u0, u1, u2, u3);
    }
    __syncthreads();
    // MFMA: A = P rows (wave's 64), B = H chunk hi/lo
    #pragma unroll
    for (int ks = 0; ks < 2; ++ks) {
      bf16x8 af[4];
      #pragma unroll
      for (int r = 0; r < 4; ++r) {
        int i = w*64 + r*16 + (lane & 15);
        int blk = (ks*4 + kg) ^ (i & 7);
        af[r] = *reinterpret_cast<const bf16x8*>(PbB + i*128 + blk*16);
      }
      #pragma unroll
      for (int c = 0; c < 8; ++c) {
        int col = c*16 + (lane & 15);
        int blk = (ks*4 + kg) ^ (col & 7);
        bf16x8 bh = *reinterpret_cast<const bf16x8*>(HhB + col*128 + blk*16);
        bf16x8 bl = *reinterpret_cast<const bf16x8*>(HlB + col*128 + blk*16);
        #pragma unroll
        for (int r = 0; r < 4; ++r) {
          acc[r][c] = __builtin_amdgcn_mfma_f32_16x16x32_bf16(af[r], bh, acc[r][c], 0, 0, 0);
          acc[r][c] = __builtin_amdgcn_mfma_f32_16x16x32_bf16(af[r], bl, acc[r][c], 0, 0, 0);
        }
      }
    }
  }

  // epilogue: ELU + store (C layout: col=lane&15, row=(lane>>4)*4+reg)
  float* __restrict__ gout = gat + ((size_t)s*BSZ + (size_t)b*NN)*HIDD;
  #pragma unroll
  for (int r = 0; r < 4; ++r) {
    int row = w*64 + r*16 + (lane >> 4)*4;
    #pragma unroll
    for (int c = 0; c < 8; ++c) {
      int col = c*16 + (lane & 15);
      #pragma unroll
      for (int i = 0; i < 4; ++i) {
        float v = acc[r][c][i];
        v = v > 0.f ? v : expm1f(v);
        gout[(size_t)(row + i)*HIDD + col] = v;
      }
    }
  }
}

// ---------------- K3: LSTM gate combine ----------------
__global__ __launch_bounds__(256) void k3_gates(const float* __restrict__ gat,
    const float* __restrict__ bi, const float* __restrict__ bfv,
    const float* __restrict__ bc, const float* __restrict__ bo,
    float* __restrict__ cstate, float* __restrict__ hmid)
{
  size_t idx = (size_t)blockIdx.x*256 + threadIdx.x;
  int hc = (int)(idx & 127);
  const size_t S = (size_t)BSZ*HIDD;
  float gi = gat[idx]       + gat[4*S+idx] + bi[hc];
  float gf = gat[S+idx]     + gat[5*S+idx] + bfv[hc];
  float gc = gat[2*S+idx]   + gat[6*S+idx] + bc[hc];
  float go = gat[3*S+idx]   + gat[7*S+idx] + bo[hc];
  float it = 1.f/(1.f+expf(-gi));
  float ft = 1.f/(1.f+expf(-gf));
  float gt = tanhf(gc);
  float ot = 1.f/(1.f+expf(-go));
  float c = ft*cstate[idx] + it*gt;
  cstate[idx] = c;
  hmid[idx] = ot*tanhf(c);
}

// ---------------- K4: node pool -> q -> qq = q@linq^T + linq_b + linh_b ----------------
__global__ __launch_bounds__(128) void k4_pool(const float* __restrict__ hmid,
    const float* __restrict__ pw, const float* __restrict__ pb,
    const float* __restrict__ lqw, const float* __restrict__ lqb,
    const float* __restrict__ lhb, float* __restrict__ qq)
{
  int b = blockIdx.x, h = threadIdx.x;
  float q = 0.f;
  for (int n = 0; n < NN; ++n)
    q += hmid[((size_t)b*NN + n)*HIDD + h] * pw[n];
  q += pb[0];
  q = fmaxf(q, 0.f);
  __shared__ float qL[HIDD];
  qL[h] = q;
  __syncthreads();
  float acc = 0.f;
  #pragma unroll 4
  for (int k = 0; k < HIDD; ++k) acc += qL[k]*lqw[h*HIDD + k];
  qq[b*HIDD + h] = acc + lqb[h] + lhb[h];
}

// ---------------- K5: t=tanh(h@linh^T+qq); a=sigmoid(t@linu^T+b); h*(1+a) ----------------
__global__ __launch_bounds__(256) void k5_fatt(const float* __restrict__ hmid,
    const float* __restrict__ lhw, const float* __restrict__ luw,
    const float* __restrict__ lub, const float* __restrict__ qq,
    float* __restrict__ hstate)
{
  const int tid = threadIdx.x, lane = tid & 63, w = tid >> 6;
  const int row0 = blockIdx.x * 32;
  const int b = row0 >> 8;                  // 32 rows never cross a batch
  __shared__ float lhT[HIDD*130];           // linh^T, f32, padded stride 130
  __shared__ float rows[4][HIDD];
  #pragma unroll
  for (int i = 0; i < 64; ++i) {
    int idx = tid + i*256;
    int hp = idx >> 7, k = idx & 127;
    lhT[k*130 + hp] = lhw[idx];
  }
  float q0 = qq[b*HIDD + 2*lane];
  float q1 = qq[b*HIDD + 2*lane + 1];
  float lu0 = luw[2*lane], lu1 = luw[2*lane+1];
  float lb = lub[0];
  __syncthreads();
  for (int chunk = 0; chunk < 8; ++chunk) {
    int r0 = row0 + chunk*4;
    #pragma unroll
    for (int i = 0; i < 2; ++i) {
      int idx = tid + i*256;
      rows[idx >> 7][idx & 127] = hmid[(size_t)r0*HIDD + idx];
    }
    __syncthreads();
    const float* R = rows[w];
    float d0 = 0.f, d1 = 0.f;
    #pragma unroll 4
    for (int k = 0; k < HIDD; ++k) {
      float2 lv = *reinterpret_cast<const float2*>(&lhT[k*130 + 2*lane]);
      float rv = R[k];
      d0 += rv*lv.x;
      d1 += rv*lv.y;
    }
    float t0 = tanhf(d0 + q0);
    float t1 = tanhf(d1 + q1);
    float ap = t0*lu0 + t1*lu1;
    #pragma unroll
    for (int off = 32; off > 0; off >>= 1) ap += __shfl_xor(ap, off, 64);
    float a = 1.f/(1.f+expf(-(ap + lb)));
    float o0 = R[2*lane]  *(1.f+a);
    float o1 = R[2*lane+1]*(1.f+a);
    reinterpret_cast<float2*>(hstate)[(size_t)(r0+w)*64 + lane] = make_float2(o0, o1);
    __syncthreads();
  }
}

// ---------------- K6: transposed write of hidden_seq ----------------
__global__ __launch_bounds__(256) void k6_tr(const float* __restrict__ hstate,
    float* __restrict__ out, int t)
{
  __shared__ float tile[128*65];
  const int r0 = blockIdx.x * 64;
  const int tid = threadIdx.x;
  #pragma unroll
  for (int i = 0; i < 32; ++i) {
    int idx = tid + i*256;
    int r = idx >> 7, h = idx & 127;
    tile[h*65 + r] = hstate[(size_t)(r0 + r)*HIDD + h];
  }
  __syncthreads();
  #pragma unroll
  for (int i = 0; i < 32; ++i) {
    int idx = tid + i*256;
    int h = idx >> 6, rr = idx & 63;
    out[(size_t)h*(TT*(size_t)BSZ) + (size_t)t*BSZ + r0 + rr] = tile[h*65 + rr];
  }
}

// ---------------- K7: append (h_T, c_T) ----------------
__global__ __launch_bounds__(256) void k7_final(const float* __restrict__ hstate,
    const float* __restrict__ cstate, float* __restrict__ out)
{
  size_t idx = (size_t)blockIdx.x*256 + threadIdx.x;
  const size_t off = (size_t)HIDD * (size_t)TT * (size_t)BSZ;  // 16777216
  out[off + idx] = hstate[idx];
  out[off + (size_t)BSZ*HIDD + idx] = cstate[idx];
}

extern "C" void kernel_launch(void* const* d_in, const int* in_sizes, int n_in,
                              void* d_out, int out_size, void* d_ws, size_t ws_size,
                              hipStream_t stream)
{
  const float* x = (const float*)d_in[0];
  GP gp;
  int wIdx[8], aIdx[8], bIdx[4];
  // setup_inputs() dict order interleaves b_g per gate group:
  //   x, [Wg_W, Wg_a, Ug_W, Ug_a, b_g] x {i,f,c,o}, pool_w, ...
  // Detect at runtime: in dict order, index 5 is b_i (128 elems).
  bool dictOrder = (in_sizes[5] == HIDD);
  if (dictOrder) {
    for (int g = 0; g < 4; ++g) {
      int base = 1 + 5*g;
      wIdx[g]   = base;     aIdx[g]   = base + 1;   // W-side GAT
      wIdx[4+g] = base + 2; aIdx[4+g] = base + 3;   // U-side GAT
      bIdx[g]   = base + 4;
    }
  } else {
    for (int g = 0; g < 4; ++g) {
      int base = 1 + 4*g;
      wIdx[g]   = base;     aIdx[g]   = base + 1;
      wIdx[4+g] = base + 2; aIdx[4+g] = base + 3;
      bIdx[g]   = 17 + g;
    }
  }
  for (int s = 0; s < 8; ++s) {
    gp.W[s] = (const float*)d_in[wIdx[s]];
    gp.A[s] = (const float*)d_in[aIdx[s]];
  }
  const float* bi  = (const float*)d_in[bIdx[0]];
  const float* bf  = (const float*)d_in[bIdx[1]];
  const float* bc  = (const float*)d_in[bIdx[2]];
  const float* bo  = (const float*)d_in[bIdx[3]];
  const float* pw  = (const float*)d_in[21];
  const float* pb  = (const float*)d_in[22];
  const float* lhw = (const float*)d_in[23];
  const float* lhb = (const float*)d_in[24];
  const float* lqw = (const float*)d_in[25];
  const float* lqb = (const float*)d_in[26];
  const float* luw = (const float*)d_in[27];
  const float* lub = (const float*)d_in[28];

  float* ws = (float*)d_ws;
  const size_t S = (size_t)BSZ*HIDD;       // 1048576
  float* hW     = ws;                      // 8*S
  float* gat    = hW + 8*S;                // 8*S
  float* hstate = gat + 8*S;               // S
  float* cstate = hstate + S;              // S
  float* hmid   = cstate + S;              // S
  float* qq     = hmid + S;                // NB*HIDD
  float* out = (float*)d_out;

  hipMemsetAsync(hstate, 0, S*sizeof(float), stream);
  hipMemsetAsync(cstate, 0, S*sizeof(float), stream);

  for (int t = 0; t < TT; ++t) {
    k1_gemm<<<dim3(256, 8), 256, 0, stream>>>(x, hstate, gp, hW, t);
    k2_attn<<<dim3(NB, 8), 256, 0, stream>>>(hW, gp, gat);
    k3_gates<<<4096, 256, 0, stream>>>(gat, bi, bf, bc, bo, cstate, hmid);
    k4_pool<<<NB, 128, 0, stream>>>(hmid, pw, pb, lqw, lqb, lhb, qq);
    k5_fatt<<<256, 256, 0, stream>>>(hmid, lhw, luw, lub, qq, hstate);
    k6_tr<<<128, 256, 0, stream>>>(hstate, out, t);
  }
  k7_final<<<4096, 256, 0, stream>>>(hstate, cstate, out);
}

// Round 4
// 2209.617 us; speedup vs baseline: 2.3906x; 1.1227x over previous
//
#include <hip/hip_runtime.h>
#include <cstdint>
#include <cstddef>

#define NN   256      // nodes
#define HIDD 128      // hidden
#define NB   32       // graphs per batch
#define TT   16       // timesteps
#define BSZ  (NB*NN)  // 8192 rows

struct GP {
  const float* W[8];  // s=0..3: Wi,Wf,Wc,Wo ; s=4..7: Ui,Uf,Uc,Uo
  const float* A[8];  // matching a-vectors (256,)
};

typedef __attribute__((ext_vector_type(8))) short bf16x8;
typedef __attribute__((ext_vector_type(4))) float f32x4;

__device__ __forceinline__ uint16_t bf16rn(float f) {
  uint32_t u = __float_as_uint(f);
  uint32_t r = u + 0x7fffu + ((u >> 16) & 1u);
  return (uint16_t)(r >> 16);
}
__device__ __forceinline__ float bf16f(uint16_t h) {
  return __uint_as_float((uint32_t)h << 16);
}

// ---------------- K1: hW[s] = src_s @ W_s  (f32) ----------------
__global__ __launch_bounds__(256) void k1_gemm(const float* __restrict__ x,
    const float* __restrict__ hstate, GP gp, float* __restrict__ hW, int t)
{
  const int s = blockIdx.y;
  const int row0 = blockIdx.x * 32;
  const int tid = threadIdx.x;
  __shared__ float srcL[32*HIDD];
  const float* __restrict__ W = gp.W[s];
  if (s < 4) {
    #pragma unroll
    for (int i = 0; i < 16; ++i) {
      int idx = tid + i*256;
      int r = idx >> 7, k = idx & 127;
      srcL[idx] = x[(size_t)(row0 + r)*(TT*HIDD) + (size_t)t*HIDD + k];
    }
  } else {
    #pragma unroll
    for (int i = 0; i < 16; ++i) {
      int idx = tid + i*256;
      srcL[idx] = hstate[(size_t)row0*HIDD + idx];
    }
  }
  __syncthreads();
  const int c2 = tid & 63;   // column pair: cols 2*c2, 2*c2+1
  const int r8 = tid >> 6;   // row group: rows r8*8 .. +7
  float acc[8][2];
  #pragma unroll
  for (int rr = 0; rr < 8; ++rr) { acc[rr][0] = 0.f; acc[rr][1] = 0.f; }
  const float2* __restrict__ W2 = reinterpret_cast<const float2*>(W);
  const float4* s4 = reinterpret_cast<const float4*>(srcL);
  for (int k4 = 0; k4 < 32; ++k4) {
    float2 w0 = W2[(k4*4+0)*64 + c2];
    float2 w1 = W2[(k4*4+1)*64 + c2];
    float2 w2 = W2[(k4*4+2)*64 + c2];
    float2 w3 = W2[(k4*4+3)*64 + c2];
    #pragma unroll
    for (int rr = 0; rr < 8; ++rr) {
      float4 sv = s4[(r8*8+rr)*32 + k4];
      acc[rr][0] += sv.x*w0.x + sv.y*w1.x + sv.z*w2.x + sv.w*w3.x;
      acc[rr][1] += sv.x*w0.y + sv.y*w1.y + sv.z*w2.y + sv.w*w3.y;
    }
  }
  float2* __restrict__ o2 = reinterpret_cast<float2*>(hW);
  #pragma unroll
  for (int rr = 0; rr < 8; ++rr) {
    int row = row0 + r8*8 + rr;
    o2[((size_t)s*BSZ + row)*64 + c2] = make_float2(acc[rr][0], acc[rr][1]);
  }
}

// ---------------- K2: gat[s] = elu(softmax(leaky(f1_i+f2_j)) @ hW) ----------------
// Block = (b, s, row-half): 128 rows. 256 threads / 4 waves. ~50 KB LDS.
__global__ __launch_bounds__(256) void k2_attn(const float* __restrict__ hW,
    GP gp, float* __restrict__ gat)
{
  const int s = blockIdx.y;
  const int b = blockIdx.x;
  const int roff = blockIdx.z * 128;
  const int tid = threadIdx.x, lane = tid & 63, w = tid >> 6;
  const int rl = tid & 127, half = tid >> 7;
  __shared__ __align__(16) float f1L[NN];
  __shared__ __align__(16) float f2L[NN];
  __shared__ __align__(16) uint16_t Pb[128*64];   // 16 KB [local row][64k] swizzled
  __shared__ __align__(16) uint16_t Hh[HIDD*64];  // 16 KB [col][64k] hi, swizzled
  __shared__ __align__(16) uint16_t Hl[HIDD*64];  // 16 KB lo
  const float* __restrict__ a1 = gp.A[s];
  const float* __restrict__ a2 = a1 + HIDD;
  const float* __restrict__ hWb = hW + ((size_t)s*BSZ + (size_t)b*NN)*HIDD;

  // phase 0: f1/f2 for all 256 nodes (node = tid)
  {
    const float4* r4  = reinterpret_cast<const float4*>(hWb + (size_t)tid*HIDD);
    const float4* A14 = reinterpret_cast<const float4*>(a1);
    const float4* A24 = reinterpret_cast<const float4*>(a2);
    float d1 = 0.f, d2 = 0.f;
    #pragma unroll 4
    for (int k4 = 0; k4 < 32; ++k4) {
      float4 v = r4[k4];
      float4 u = A14[k4], q = A24[k4];
      d1 += v.x*u.x + v.y*u.y + v.z*u.z + v.w*u.w;
      d2 += v.x*q.x + v.y*q.y + v.z*q.z + v.w*q.w;
    }
    f1L[tid] = d1;
    f2L[tid] = d2;
  }
  __syncthreads();

  // phase 1: softmax stats for row roff+rl, j-half = half (32 of 64 j4-groups)
  float* scr = reinterpret_cast<float*>(Pb);
  const float4* f24 = reinterpret_cast<const float4*>(f2L);
  const float f1v = f1L[roff + rl];
  float m = -1e30f;
  #pragma unroll
  for (int g = 0; g < 4; ++g) {
    #pragma unroll
    for (int ii = 0; ii < 8; ++ii) {
      float4 v = f24[g*16 + half*8 + ii];
      float e0 = f1v + v.x; e0 = e0 > 0.f ? e0 : 0.01f*e0;
      float e1 = f1v + v.y; e1 = e1 > 0.f ? e1 : 0.01f*e1;
      float e2 = f1v + v.z; e2 = e2 > 0.f ? e2 : 0.01f*e2;
      float e3 = f1v + v.w; e3 = e3 > 0.f ? e3 : 0.01f*e3;
      m = fmaxf(m, fmaxf(fmaxf(e0, e1), fmaxf(e2, e3)));
    }
  }
  scr[tid] = m;
  __syncthreads();
  m = fmaxf(scr[rl], scr[rl + 128]);
  float ssum = 0.f;
  #pragma unroll
  for (int g = 0; g < 4; ++g) {
    #pragma unroll
    for (int ii = 0; ii < 8; ++ii) {
      float4 v = f24[g*16 + half*8 + ii];
      float e0 = f1v + v.x; e0 = e0 > 0.f ? e0 : 0.01f*e0;
      float e1 = f1v + v.y; e1 = e1 > 0.f ? e1 : 0.01f*e1;
      float e2 = f1v + v.z; e2 = e2 > 0.f ? e2 : 0.01f*e2;
      float e3 = f1v + v.w; e3 = e3 > 0.f ? e3 : 0.01f*e3;
      ssum += expf(e0 - m) + expf(e1 - m) + expf(e2 - m) + expf(e3 - m);
    }
  }
  scr[256 + tid] = ssum;
  __syncthreads();
  ssum = scr[256 + rl] + scr[256 + rl + 128];
  const float rs = 1.f / ssum;

  f32x4 acc[2][8];
  #pragma unroll
  for (int r = 0; r < 2; ++r)
    #pragma unroll
    for (int c = 0; c < 8; ++c)
      acc[r][c] = (f32x4){0.f, 0.f, 0.f, 0.f};

  char* PbB = reinterpret_cast<char*>(Pb);
  char* HhB = reinterpret_cast<char*>(Hh);
  char* HlB = reinterpret_cast<char*>(Hl);
  const int kg = lane >> 4;

  for (int kc = 0; kc < 4; ++kc) {
    __syncthreads();   // previous chunk's MFMA reads done / scratch reads done
    // stage H chunk [col][64k] hi/lo as full b128 blocks (conflict-free writes)
    #pragma unroll
    for (int it = 0; it < 4; ++it) {
      int idx = it*256 + tid;
      int c = idx & 127, kg4 = idx >> 7;      // kg4 = 16B block = 8 k's
      float v[8];
      #pragma unroll
      for (int mi = 0; mi < 8; ++mi)
        v[mi] = hWb[(size_t)(kc*64 + kg4*8 + mi)*HIDD + c];
      uint32_t uh[4], ul[4];
      #pragma unroll
      for (int j = 0; j < 4; ++j) {
        uint16_t h0 = bf16rn(v[2*j]), h1 = bf16rn(v[2*j+1]);
        uint16_t l0 = bf16rn(v[2*j]   - bf16f(h0));
        uint16_t l1 = bf16rn(v[2*j+1] - bf16f(h1));
        uh[j] = (uint32_t)h0 | ((uint32_t)h1 << 16);
        ul[j] = (uint32_t)l0 | ((uint32_t)l1 << 16);
      }
      int off = c*128 + ((kg4 ^ (c & 7)) << 4);
      *reinterpret_cast<uint4*>(HhB + off) = make_uint4(uh[0], uh[1], uh[2], uh[3]);
      *reinterpret_cast<uint4*>(HlB + off) = make_uint4(ul[0], ul[1], ul[2], ul[3]);
    }
    // P-gen for local row rl, this thread's 4 blocks (j-half)
    #pragma unroll
    for (int bb = 0; bb < 4; ++bb) {
      int blk = half*4 + bb;
      float4 va = f24[kc*16 + blk*2];
      float4 vb = f24[kc*16 + blk*2 + 1];
      float e0 = f1v + va.x; e0 = e0 > 0.f ? e0 : 0.01f*e0;
      float e1 = f1v + va.y; e1 = e1 > 0.f ? e1 : 0.01f*e1;
      float e2 = f1v + va.z; e2 = e2 > 0.f ? e2 : 0.01f*e2;
      float e3 = f1v + va.w; e3 = e3 > 0.f ? e3 : 0.01f*e3;
      float e4 = f1v + vb.x; e4 = e4 > 0.f ? e4 : 0.01f*e4;
      float e5 = f1v + vb.y; e5 = e5 > 0.f ? e5 : 0.01f*e5;
      float e6 = f1v + vb.z; e6 = e6 > 0.f ? e6 : 0.01f*e6;
      float e7 = f1v + vb.w; e7 = e7 > 0.f ? e7 : 0.01f*e7;
      float p0 = expf(e0 - m)*rs, p1 = expf(e1 - m)*rs;
      float p2 = expf(e2 - m)*rs, p3 = expf(e3 - m)*rs;
      float p4 = expf(e4 - m)*rs, p5 = expf(e5 - m)*rs;
      float p6 = expf(e6 - m)*rs, p7 = expf(e7 - m)*rs;
      uint32_t u0 = (uint32_t)bf16rn(p0) | ((uint32_t)bf16rn(p1) << 16);
      uint32_t u1 = (uint32_t)bf16rn(p2) | ((uint32_t)bf16rn(p3) << 16);
      uint32_t u2 = (uint32_t)bf16rn(p4) | ((uint32_t)bf16rn(p5) << 16);
      uint32_t u3 = (uint32_t)bf16rn(p6) | ((uint32_t)bf16rn(p7) << 16);
      *reinterpret_cast<uint4*>(PbB + rl*128 + ((blk ^ (rl & 7)) << 4)) =
          make_uint4(u0, u1, u2, u3);
    }
    __syncthreads();
    // MFMA: A = P rows (wave's 32 local rows), B = H chunk hi/lo
    #pragma unroll
    for (int ks = 0; ks < 2; ++ks) {
      bf16x8 af[2];
      #pragma unroll
      for (int r = 0; r < 2; ++r) {
        int i = w*32 + r*16 + (lane & 15);
        int blk = (ks*4 + kg) ^ (i & 7);
        af[r] = *reinterpret_cast<const bf16x8*>(PbB + i*128 + blk*16);
      }
      #pragma unroll
      for (int c = 0; c < 8; ++c) {
        int col = c*16 + (lane & 15);
        int blk = (ks*4 + kg) ^ (col & 7);
        bf16x8 bh = *reinterpret_cast<const bf16x8*>(HhB + col*128 + blk*16);
        bf16x8 bl = *reinterpret_cast<const bf16x8*>(HlB + col*128 + blk*16);
        #pragma unroll
        for (int r = 0; r < 2; ++r) {
          acc[r][c] = __builtin_amdgcn_mfma_f32_16x16x32_bf16(af[r], bh, acc[r][c], 0, 0, 0);
          acc[r][c] = __builtin_amdgcn_mfma_f32_16x16x32_bf16(af[r], bl, acc[r][c], 0, 0, 0);
        }
      }
    }
  }

  // epilogue: ELU + store (C layout: col=lane&15, row=(lane>>4)*4+reg)
  float* __restrict__ gout = gat + ((size_t)s*BSZ + (size_t)b*NN)*HIDD;
  #pragma unroll
  for (int r = 0; r < 2; ++r) {
    int row = roff + w*32 + r*16 + (lane >> 4)*4;
    #pragma unroll
    for (int c = 0; c < 8; ++c) {
      int col = c*16 + (lane & 15);
      #pragma unroll
      for (int i = 0; i < 4; ++i) {
        float v = acc[r][c][i];
        v = v > 0.f ? v : expm1f(v);
        gout[(size_t)(row + i)*HIDD + col] = v;
      }
    }
  }
}

// ---------------- K3: LSTM gate combine ----------------
__global__ __launch_bounds__(256) void k3_gates(const float* __restrict__ gat,
    const float* __restrict__ bi, const float* __restrict__ bfv,
    const float* __restrict__ bc, const float* __restrict__ bo,
    float* __restrict__ cstate, float* __restrict__ hmid)
{
  size_t idx = (size_t)blockIdx.x*256 + threadIdx.x;
  int hc = (int)(idx & 127);
  const size_t S = (size_t)BSZ*HIDD;
  float gi = gat[idx]       + gat[4*S+idx] + bi[hc];
  float gf = gat[S+idx]     + gat[5*S+idx] + bfv[hc];
  float gc = gat[2*S+idx]   + gat[6*S+idx] + bc[hc];
  float go = gat[3*S+idx]   + gat[7*S+idx] + bo[hc];
  float it = 1.f/(1.f+expf(-gi));
  float ft = 1.f/(1.f+expf(-gf));
  float gt = tanhf(gc);
  float ot = 1.f/(1.f+expf(-go));
  float c = ft*cstate[idx] + it*gt;
  cstate[idx] = c;
  hmid[idx] = ot*tanhf(c);
}

// ---------------- K4: node pool -> q -> qq = q@linq^T + linq_b + linh_b ----------------
__global__ __launch_bounds__(128) void k4_pool(const float* __restrict__ hmid,
    const float* __restrict__ pw, const float* __restrict__ pb,
    const float* __restrict__ lqw, const float* __restrict__ lqb,
    const float* __restrict__ lhb, float* __restrict__ qq)
{
  int b = blockIdx.x, h = threadIdx.x;
  float q = 0.f;
  for (int n = 0; n < NN; ++n)
    q += hmid[((size_t)b*NN + n)*HIDD + h] * pw[n];
  q += pb[0];
  q = fmaxf(q, 0.f);
  __shared__ float qL[HIDD];
  qL[h] = q;
  __syncthreads();
  float acc = 0.f;
  #pragma unroll 4
  for (int k = 0; k < HIDD; ++k) acc += qL[k]*lqw[h*HIDD + k];
  qq[b*HIDD + h] = acc + lqb[h] + lhb[h];
}

// ---------------- K5: fatt + residual + hstate + transposed hidden_seq write ----------------
__global__ __launch_bounds__(256) void k5_fatt(const float* __restrict__ hmid,
    const float* __restrict__ lhw, const float* __restrict__ luw,
    const float* __restrict__ lub, const float* __restrict__ qq,
    float* __restrict__ hstate, float* __restrict__ out, int t)
{
  const int tid = threadIdx.x, lane = tid & 63, w = tid >> 6;
  const int row0 = blockIdx.x * 32;
  const int b = row0 >> 8;                  // 32 rows never cross a batch
  __shared__ float lhT[HIDD*129];           // linh^T, f32, stride 129 (conflict-free)
  __shared__ float rows[4][HIDD];
  __shared__ float otile[HIDD][33];         // [h][local row]
  #pragma unroll
  for (int i = 0; i < 64; ++i) {
    int idx = tid + i*256;
    int hp = idx >> 7, k = idx & 127;
    lhT[k*129 + hp] = lhw[idx];
  }
  float qv0 = qq[b*HIDD + lane];
  float qv1 = qq[b*HIDD + 64 + lane];
  float lu0 = luw[lane], lu1 = luw[64 + lane];
  float lb = lub[0];
  __syncthreads();
  for (int chunk = 0; chunk < 8; ++chunk) {
    int r0 = row0 + chunk*4;
    #pragma unroll
    for (int i = 0; i < 2; ++i) {
      int idx = tid + i*256;
      rows[idx >> 7][idx & 127] = hmid[(size_t)r0*HIDD + idx];
    }
    __syncthreads();
    const float* R = rows[w];
    float d0 = 0.f, d1 = 0.f;
    #pragma unroll 4
    for (int k = 0; k < HIDD; ++k) {
      float rv = R[k];
      d0 += rv*lhT[k*129 + lane];
      d1 += rv*lhT[k*129 + 64 + lane];
    }
    float t0 = tanhf(d0 + qv0);
    float t1 = tanhf(d1 + qv1);
    float ap = t0*lu0 + t1*lu1;
    #pragma unroll
    for (int off = 32; off > 0; off >>= 1) ap += __shfl_xor(ap, off, 64);
    float a = 1.f/(1.f+expf(-(ap + lb)));
    float o0 = R[lane]     *(1.f+a);
    float o1 = R[64 + lane]*(1.f+a);
    int row = r0 + w, rr = chunk*4 + w;
    hstate[(size_t)row*HIDD + lane]      = o0;
    hstate[(size_t)row*HIDD + 64 + lane] = o1;
    otile[lane][rr]      = o0;
    otile[64 + lane][rr] = o1;
    __syncthreads();
  }
  // transposed hidden_seq write: out[h][t*BSZ + row0 + rr]
  #pragma unroll
  for (int i = 0; i < 16; ++i) {
    int idx = tid + i*256;
    int h = idx >> 5, rr = idx & 31;
    out[(size_t)h*(TT*(size_t)BSZ) + (size_t)t*BSZ + row0 + rr] = otile[h][rr];
  }
}

// ---------------- K7: append (h_T, c_T) ----------------
__global__ __launch_bounds__(256) void k7_final(const float* __restrict__ hstate,
    const float* __restrict__ cstate, float* __restrict__ out)
{
  size_t idx = (size_t)blockIdx.x*256 + threadIdx.x;
  const size_t off = (size_t)HIDD * (size_t)TT * (size_t)BSZ;  // 16777216
  out[off + idx] = hstate[idx];
  out[off + (size_t)BSZ*HIDD + idx] = cstate[idx];
}

extern "C" void kernel_launch(void* const* d_in, const int* in_sizes, int n_in,
                              void* d_out, int out_size, void* d_ws, size_t ws_size,
                              hipStream_t stream)
{
  const float* x = (const float*)d_in[0];
  GP gp;
  int wIdx[8], aIdx[8], bIdx[4];
  // setup_inputs() dict order interleaves b_g per gate group.
  bool dictOrder = (in_sizes[5] == HIDD);
  if (dictOrder) {
    for (int g = 0; g < 4; ++g) {
      int base = 1 + 5*g;
      wIdx[g]   = base;     aIdx[g]   = base + 1;   // W-side GAT
      wIdx[4+g] = base + 2; aIdx[4+g] = base + 3;   // U-side GAT
      bIdx[g]   = base + 4;
    }
  } else {
    for (int g = 0; g < 4; ++g) {
      int base = 1 + 4*g;
      wIdx[g]   = base;     aIdx[g]   = base + 1;
      wIdx[4+g] = base + 2; aIdx[4+g] = base + 3;
      bIdx[g]   = 17 + g;
    }
  }
  for (int s = 0; s < 8; ++s) {
    gp.W[s] = (const float*)d_in[wIdx[s]];
    gp.A[s] = (const float*)d_in[aIdx[s]];
  }
  const float* bi  = (const float*)d_in[bIdx[0]];
  const float* bf  = (const float*)d_in[bIdx[1]];
  const float* bc  = (const float*)d_in[bIdx[2]];
  const float* bo  = (const float*)d_in[bIdx[3]];
  const float* pw  = (const float*)d_in[21];
  const float* pb  = (const float*)d_in[22];
  const float* lhw = (const float*)d_in[23];
  const float* lhb = (const float*)d_in[24];
  const float* lqw = (const float*)d_in[25];
  const float* lqb = (const float*)d_in[26];
  const float* luw = (const float*)d_in[27];
  const float* lub = (const float*)d_in[28];

  float* ws = (float*)d_ws;
  const size_t S = (size_t)BSZ*HIDD;       // 1048576
  float* hW     = ws;                      // 8*S
  float* gat    = hW + 8*S;                // 8*S
  float* hstate = gat + 8*S;               // S
  float* cstate = hstate + S;              // S
  float* hmid   = cstate + S;              // S
  float* qq     = hmid + S;                // NB*HIDD
  float* out = (float*)d_out;

  hipMemsetAsync(hstate, 0, S*sizeof(float), stream);
  hipMemsetAsync(cstate, 0, S*sizeof(float), stream);

  for (int t = 0; t < TT; ++t) {
    k1_gemm<<<dim3(256, 8), 256, 0, stream>>>(x, hstate, gp, hW, t);
    k2_attn<<<dim3(NB, 8, 2), 256, 0, stream>>>(hW, gp, gat);
    k3_gates<<<4096, 256, 0, stream>>>(gat, bi, bf, bc, bo, cstate, hmid);
    k4_pool<<<NB, 128, 0, stream>>>(hmid, pw, pb, lqw, lqb, lhb, qq);
    k5_fatt<<<256, 256, 0, stream>>>(hmid, lhw, luw, lub, qq, hstate, out, t);
  }
  k7_final<<<4096, 256, 0, stream>>>(hstate, cstate, out);
}

// Round 5
// 1678.144 us; speedup vs baseline: 3.1477x; 1.3167x over previous
//
#include <hip/hip_runtime.h>
#include <cstdint>
#include <cstddef>

#define NN   256      // nodes
#define HIDD 128      // hidden
#define NB   32       // graphs per batch
#define TT   16       // timesteps
#define BSZ  (NB*NN)  // 8192 rows

struct GP {
  const float* W[8];  // s=0..3: Wi,Wf,Wc,Wo ; s=4..7: Ui,Uf,Uc,Uo
  const float* A[8];  // matching a-vectors (256,)
};

typedef __attribute__((ext_vector_type(8))) short bf16x8;
typedef __attribute__((ext_vector_type(4))) float f32x4;

__device__ __forceinline__ uint16_t bf16rn(float f) {
  uint32_t u = __float_as_uint(f);
  uint32_t r = u + 0x7fffu + ((u >> 16) & 1u);
  return (uint16_t)(r >> 16);
}
__device__ __forceinline__ float bf16f(uint16_t h) {
  return __uint_as_float((uint32_t)h << 16);
}

// ---------------- K0: pre-convert W[s] to fragment-ordered bf16 hi/lo ----------------
// Layout per s: 16B-block index f = (cf*4 + ks)*64 + l  (cf=col-frag 0..7, ks=k-step 0..3,
// l=lane 0..63). Block holds W[k][col] for col=cf*16+(l&15), k=(ks*4+(l>>4))*8+j, j=0..7.
__global__ __launch_bounds__(256) void k0_convw(GP gp, uint4* __restrict__ WfH,
    uint4* __restrict__ WfL)
{
  const int s = blockIdx.x;
  const float* __restrict__ W = gp.W[s];
  const int tid = threadIdx.x;
  #pragma unroll
  for (int it = 0; it < 8; ++it) {
    int f = it*256 + tid;               // 0..2047
    int cf = f >> 8, ks = (f >> 6) & 3, l = f & 63;
    int col = cf*16 + (l & 15);
    int kbase = (ks*4 + (l >> 4))*8;
    float v[8];
    #pragma unroll
    for (int j = 0; j < 8; ++j) v[j] = W[(kbase + j)*HIDD + col];
    uint32_t uh[4], ul[4];
    #pragma unroll
    for (int j = 0; j < 4; ++j) {
      uint16_t h0 = bf16rn(v[2*j]), h1 = bf16rn(v[2*j+1]);
      uint16_t l0 = bf16rn(v[2*j]   - bf16f(h0));
      uint16_t l1 = bf16rn(v[2*j+1] - bf16f(h1));
      uh[j] = (uint32_t)h0 | ((uint32_t)h1 << 16);
      ul[j] = (uint32_t)l0 | ((uint32_t)l1 << 16);
    }
    WfH[s*2048 + f] = make_uint4(uh[0], uh[1], uh[2], uh[3]);
    WfL[s*2048 + f] = make_uint4(ul[0], ul[1], ul[2], ul[3]);
  }
}

// ---------------- K1: hW[s] = src_s @ W_s via split-bf16 MFMA ----------------
// Block: 128 rows x 128 cols, 4 waves (each wave 32 rows). Grid (64, 8).
__global__ __launch_bounds__(256) void k1_gemm(const float* __restrict__ x,
    const float* __restrict__ hstate, GP gp, const uint4* __restrict__ WfH,
    const uint4* __restrict__ WfL, float* __restrict__ hW, int t)
{
  const int s = blockIdx.y;
  const int row0 = blockIdx.x * 128;
  const int tid = threadIdx.x, lane = tid & 63, w = tid >> 6;
  __shared__ uint4 AH[128*16];   // 32 KB  [row][16B-block], swizzled
  __shared__ uint4 AL[128*16];   // 32 KB
  // stage src rows as hi/lo bf16
  #pragma unroll
  for (int it = 0; it < 8; ++it) {
    int linear = it*256 + tid;          // 0..2047
    int r = linear >> 4, blk = linear & 15;
    const float4* p;
    if (s < 4) p = reinterpret_cast<const float4*>(x + (size_t)(row0 + r)*(TT*HIDD) + (size_t)t*HIDD);
    else       p = reinterpret_cast<const float4*>(hstate + (size_t)(row0 + r)*HIDD);
    float4 v0 = p[blk*2], v1 = p[blk*2 + 1];
    float vv[8] = {v0.x, v0.y, v0.z, v0.w, v1.x, v1.y, v1.z, v1.w};
    uint32_t uh[4], ul[4];
    #pragma unroll
    for (int j = 0; j < 4; ++j) {
      uint16_t h0 = bf16rn(vv[2*j]), h1 = bf16rn(vv[2*j+1]);
      uint16_t l0 = bf16rn(vv[2*j]   - bf16f(h0));
      uint16_t l1 = bf16rn(vv[2*j+1] - bf16f(h1));
      uh[j] = (uint32_t)h0 | ((uint32_t)h1 << 16);
      ul[j] = (uint32_t)l0 | ((uint32_t)l1 << 16);
    }
    int dst = r*16 + (blk ^ (r & 7));
    AH[dst] = make_uint4(uh[0], uh[1], uh[2], uh[3]);
    AL[dst] = make_uint4(ul[0], ul[1], ul[2], ul[3]);
  }
  __syncthreads();
  const int kg = lane >> 4;
  bf16x8 ah[2][4], al[2][4];
  #pragma unroll
  for (int r = 0; r < 2; ++r) {
    int i = w*32 + r*16 + (lane & 15);
    #pragma unroll
    for (int ks = 0; ks < 4; ++ks) {
      int blk = (ks*4 + kg) ^ (i & 7);
      ah[r][ks] = *reinterpret_cast<const bf16x8*>(&AH[i*16 + blk]);
      al[r][ks] = *reinterpret_cast<const bf16x8*>(&AL[i*16 + blk]);
    }
  }
  f32x4 acc[2][8];
  #pragma unroll
  for (int r = 0; r < 2; ++r)
    #pragma unroll
    for (int c = 0; c < 8; ++c)
      acc[r][c] = (f32x4){0.f, 0.f, 0.f, 0.f};
  const uint4* __restrict__ BH = WfH + s*2048;
  const uint4* __restrict__ BL = WfL + s*2048;
  #pragma unroll
  for (int cf = 0; cf < 8; ++cf) {
    bf16x8 bh[4], bl[4];
    #pragma unroll
    for (int ks = 0; ks < 4; ++ks) {
      bh[ks] = *reinterpret_cast<const bf16x8*>(&BH[(cf*4 + ks)*64 + lane]);
      bl[ks] = *reinterpret_cast<const bf16x8*>(&BL[(cf*4 + ks)*64 + lane]);
    }
    #pragma unroll
    for (int ks = 0; ks < 4; ++ks) {
      #pragma unroll
      for (int r = 0; r < 2; ++r) {
        acc[r][cf] = __builtin_amdgcn_mfma_f32_16x16x32_bf16(ah[r][ks], bh[ks], acc[r][cf], 0, 0, 0);
        acc[r][cf] = __builtin_amdgcn_mfma_f32_16x16x32_bf16(al[r][ks], bh[ks], acc[r][cf], 0, 0, 0);
        acc[r][cf] = __builtin_amdgcn_mfma_f32_16x16x32_bf16(ah[r][ks], bl[ks], acc[r][cf], 0, 0, 0);
      }
    }
  }
  float* __restrict__ o = hW + ((size_t)s*BSZ + row0)*HIDD;
  #pragma unroll
  for (int r = 0; r < 2; ++r) {
    int rbase = w*32 + r*16 + (lane >> 4)*4;
    #pragma unroll
    for (int cf = 0; cf < 8; ++cf) {
      int col = cf*16 + (lane & 15);
      #pragma unroll
      for (int ii = 0; ii < 4; ++ii)
        o[(size_t)(rbase + ii)*HIDD + col] = acc[r][cf][ii];
    }
  }
}

// ---------------- K2: gat[s] = elu(softmax(leaky(f1_i+f2_j)) @ hW) ----------------
// Single-pass softmax (no max-shift; e is O(+-5)). P stored unnormalized bf16;
// normalization by 1/rowsum in the epilogue. PV via MFMA, H split hi/lo bf16.
__global__ __launch_bounds__(256) void k2_attn(const float* __restrict__ hW,
    GP gp, float* __restrict__ gat)
{
  const int s = blockIdx.y;
  const int b = blockIdx.x;
  const int roff = blockIdx.z * 128;
  const int tid = threadIdx.x, lane = tid & 63, w = tid >> 6;
  const int rl = tid & 127, half = tid >> 7;
  __shared__ __align__(16) float f1L[NN];
  __shared__ __align__(16) float f2L[NN];
  __shared__ __align__(16) float sums[256];
  __shared__ __align__(16) uint16_t Pb[128*64];   // 16 KB [local row][64k] swizzled
  __shared__ __align__(16) uint16_t Hh[HIDD*64];  // 16 KB [col][64k] hi, swizzled
  __shared__ __align__(16) uint16_t Hl[HIDD*64];  // 16 KB lo
  const float* __restrict__ a1 = gp.A[s];
  const float* __restrict__ a2 = a1 + HIDD;
  const float* __restrict__ hWb = hW + ((size_t)s*BSZ + (size_t)b*NN)*HIDD;

  // phase 0: f1/f2 for all 256 nodes (node = tid)
  {
    const float4* r4  = reinterpret_cast<const float4*>(hWb + (size_t)tid*HIDD);
    const float4* A14 = reinterpret_cast<const float4*>(a1);
    const float4* A24 = reinterpret_cast<const float4*>(a2);
    float d1 = 0.f, d2 = 0.f;
    #pragma unroll 4
    for (int k4 = 0; k4 < 32; ++k4) {
      float4 v = r4[k4];
      float4 u = A14[k4], q = A24[k4];
      d1 += v.x*u.x + v.y*u.y + v.z*u.z + v.w*u.w;
      d2 += v.x*q.x + v.y*q.y + v.z*q.z + v.w*q.w;
    }
    f1L[tid] = d1;
    f2L[tid] = d2;
  }
  __syncthreads();

  const float4* f24 = reinterpret_cast<const float4*>(f2L);
  const float f1v = f1L[roff + rl];
  float ssum = 0.f;

  f32x4 acc[2][8];
  #pragma unroll
  for (int r = 0; r < 2; ++r)
    #pragma unroll
    for (int c = 0; c < 8; ++c)
      acc[r][c] = (f32x4){0.f, 0.f, 0.f, 0.f};

  char* PbB = reinterpret_cast<char*>(Pb);
  char* HhB = reinterpret_cast<char*>(Hh);
  char* HlB = reinterpret_cast<char*>(Hl);
  const int kg = lane >> 4;

  for (int kc = 0; kc < 4; ++kc) {
    __syncthreads();   // previous chunk's MFMA reads done
    // stage H chunk [col][64k] hi/lo as full b128 blocks
    #pragma unroll
    for (int it = 0; it < 4; ++it) {
      int idx = it*256 + tid;
      int c = idx & 127, kg4 = idx >> 7;      // kg4 = 16B block = 8 k's
      float v[8];
      #pragma unroll
      for (int mi = 0; mi < 8; ++mi)
        v[mi] = hWb[(size_t)(kc*64 + kg4*8 + mi)*HIDD + c];
      uint32_t uh[4], ul[4];
      #pragma unroll
      for (int j = 0; j < 4; ++j) {
        uint16_t h0 = bf16rn(v[2*j]), h1 = bf16rn(v[2*j+1]);
        uint16_t l0 = bf16rn(v[2*j]   - bf16f(h0));
        uint16_t l1 = bf16rn(v[2*j+1] - bf16f(h1));
        uh[j] = (uint32_t)h0 | ((uint32_t)h1 << 16);
        ul[j] = (uint32_t)l0 | ((uint32_t)l1 << 16);
      }
      int off = c*128 + ((kg4 ^ (c & 7)) << 4);
      *reinterpret_cast<uint4*>(HhB + off) = make_uint4(uh[0], uh[1], uh[2], uh[3]);
      *reinterpret_cast<uint4*>(HlB + off) = make_uint4(ul[0], ul[1], ul[2], ul[3]);
    }
    // P-gen for local row rl, this thread's 4 blocks (j-half); accumulate row-sum
    #pragma unroll
    for (int bb = 0; bb < 4; ++bb) {
      int blk = half*4 + bb;
      float4 va = f24[kc*16 + blk*2];
      float4 vb = f24[kc*16 + blk*2 + 1];
      float e0 = f1v + va.x; e0 = e0 > 0.f ? e0 : 0.01f*e0;
      float e1 = f1v + va.y; e1 = e1 > 0.f ? e1 : 0.01f*e1;
      float e2 = f1v + va.z; e2 = e2 > 0.f ? e2 : 0.01f*e2;
      float e3 = f1v + va.w; e3 = e3 > 0.f ? e3 : 0.01f*e3;
      float e4 = f1v + vb.x; e4 = e4 > 0.f ? e4 : 0.01f*e4;
      float e5 = f1v + vb.y; e5 = e5 > 0.f ? e5 : 0.01f*e5;
      float e6 = f1v + vb.z; e6 = e6 > 0.f ? e6 : 0.01f*e6;
      float e7 = f1v + vb.w; e7 = e7 > 0.f ? e7 : 0.01f*e7;
      float p0 = expf(e0), p1 = expf(e1), p2 = expf(e2), p3 = expf(e3);
      float p4 = expf(e4), p5 = expf(e5), p6 = expf(e6), p7 = expf(e7);
      ssum += (p0 + p1) + (p2 + p3) + ((p4 + p5) + (p6 + p7));
      uint32_t u0 = (uint32_t)bf16rn(p0) | ((uint32_t)bf16rn(p1) << 16);
      uint32_t u1 = (uint32_t)bf16rn(p2) | ((uint32_t)bf16rn(p3) << 16);
      uint32_t u2 = (uint32_t)bf16rn(p4) | ((uint32_t)bf16rn(p5) << 16);
      uint32_t u3 = (uint32_t)bf16rn(p6) | ((uint32_t)bf16rn(p7) << 16);
      *reinterpret_cast<uint4*>(PbB + rl*128 + ((blk ^ (rl & 7)) << 4)) =
          make_uint4(u0, u1, u2, u3);
    }
    __syncthreads();
    // MFMA: A = P rows (wave's 32 local rows), B = H chunk hi/lo
    #pragma unroll
    for (int ks = 0; ks < 2; ++ks) {
      bf16x8 af[2];
      #pragma unroll
      for (int r = 0; r < 2; ++r) {
        int i = w*32 + r*16 + (lane & 15);
        int blk = (ks*4 + kg) ^ (i & 7);
        af[r] = *reinterpret_cast<const bf16x8*>(PbB + i*128 + blk*16);
      }
      #pragma unroll
      for (int c = 0; c < 8; ++c) {
        int col = c*16 + (lane & 15);
        int blk = (ks*4 + kg) ^ (col & 7);
        bf16x8 bh = *reinterpret_cast<const bf16x8*>(HhB + col*128 + blk*16);
        bf16x8 bl = *reinterpret_cast<const bf16x8*>(HlB + col*128 + blk*16);
        #pragma unroll
        for (int r = 0; r < 2; ++r) {
          acc[r][c] = __builtin_amdgcn_mfma_f32_16x16x32_bf16(af[r], bh, acc[r][c], 0, 0, 0);
          acc[r][c] = __builtin_amdgcn_mfma_f32_16x16x32_bf16(af[r], bl, acc[r][c], 0, 0, 0);
        }
      }
    }
  }
  sums[tid] = ssum;
  __syncthreads();

  // epilogue: normalize + ELU + store (C layout: col=lane&15, row=(lane>>4)*4+reg)
  float* __restrict__ gout = gat + ((size_t)s*BSZ + (size_t)b*NN)*HIDD;
  #pragma unroll
  for (int r = 0; r < 2; ++r) {
    int lrb = w*32 + r*16 + (lane >> 4)*4;
    int row = roff + lrb;
    #pragma unroll
    for (int ii = 0; ii < 4; ++ii) {
      float rs = 1.f / (sums[lrb + ii] + sums[128 + lrb + ii]);
      #pragma unroll
      for (int c = 0; c < 8; ++c) {
        int col = c*16 + (lane & 15);
        float v = acc[r][c][ii] * rs;
        v = v > 0.f ? v : expm1f(v);
        gout[(size_t)(row + ii)*HIDD + col] = v;
      }
    }
  }
}

// ---------------- K3: LSTM gate combine (float4) ----------------
__global__ __launch_bounds__(256) void k3_gates(const float4* __restrict__ gat4,
    const float4* __restrict__ bi4, const float4* __restrict__ bf4,
    const float4* __restrict__ bc4, const float4* __restrict__ bo4,
    float4* __restrict__ c4, float4* __restrict__ hm4, float4* __restrict__ outc4)
{
  const size_t S4 = (size_t)BSZ*HIDD/4;
  size_t idx = (size_t)blockIdx.x*256 + threadIdx.x;
  int hc = (int)(idx & 31);
  float4 gi = gat4[idx], gf = gat4[S4+idx], gc = gat4[2*S4+idx], go = gat4[3*S4+idx];
  float4 ui = gat4[4*S4+idx], uf = gat4[5*S4+idx], uc = gat4[6*S4+idx], uo = gat4[7*S4+idx];
  float4 Bi = bi4[hc], Bf = bf4[hc], Bc = bc4[hc], Bo = bo4[hc];
  float4 cv = c4[idx], hv, cn;
  #pragma unroll
  for (int j = 0; j < 4; ++j) {
    float xi = (&gi.x)[j] + (&ui.x)[j] + (&Bi.x)[j];
    float xf = (&gf.x)[j] + (&uf.x)[j] + (&Bf.x)[j];
    float xc = (&gc.x)[j] + (&uc.x)[j] + (&Bc.x)[j];
    float xo = (&go.x)[j] + (&uo.x)[j] + (&Bo.x)[j];
    float it = 1.f/(1.f+expf(-xi));
    float ft = 1.f/(1.f+expf(-xf));
    float gt = tanhf(xc);
    float ot = 1.f/(1.f+expf(-xo));
    float c = ft*(&cv.x)[j] + it*gt;
    (&cn.x)[j] = c;
    (&hv.x)[j] = ot*tanhf(c);
  }
  c4[idx] = cn;
  hm4[idx] = hv;
  if (outc4) outc4[idx] = cn;
}

// ---------------- K5: pool + qq + fatt + residual + transposed seq write ----------------
__global__ __launch_bounds__(256) void k5_fatt(const float* __restrict__ hmid,
    const float* __restrict__ pw, const float* __restrict__ pb,
    const float* __restrict__ lqw, const float* __restrict__ lqb,
    const float* __restrict__ lhb, const float* __restrict__ lhw,
    const float* __restrict__ luw, const float* __restrict__ lub,
    float* __restrict__ hstate, float* __restrict__ out, int t,
    float* __restrict__ outh)
{
  const int tid = threadIdx.x, lane = tid & 63, w = tid >> 6;
  const int row0 = blockIdx.x * 32;
  const int b = row0 >> 8;                  // 32 rows never cross a batch
  __shared__ float lhT[HIDD*129];           // linh^T, f32, stride 129
  __shared__ float rows[4][HIDD];
  __shared__ float otile[HIDD][33];         // [h][local row]
  __shared__ float qsum[256];
  __shared__ float qqL[HIDD];
  #pragma unroll
  for (int i = 0; i < 64; ++i) {
    int idx = tid + i*256;
    int hp = idx >> 7, k = idx & 127;
    lhT[k*129 + hp] = lhw[idx];
  }
  // pool: thread (h=tid&127, half=tid>>7) sums its 128 nodes
  {
    const int h = tid & 127, half = tid >> 7;
    const float* hb = hmid + (size_t)b*NN*HIDD;
    float qacc = 0.f;
    #pragma unroll 4
    for (int n = half*128; n < half*128 + 128; ++n)
      qacc += hb[(size_t)n*HIDD + h] * pw[n];
    qsum[tid] = qacc;
  }
  __syncthreads();
  if (tid < 128) {
    float q = fmaxf(qsum[tid] + qsum[128 + tid] + pb[0], 0.f);
    qsum[tid] = q;          // now holds qL
  }
  __syncthreads();
  if (tid < 128) {
    float acc = 0.f;
    #pragma unroll 4
    for (int k = 0; k < HIDD; ++k) acc += qsum[k]*lqw[tid*HIDD + k];
    qqL[tid] = acc + lqb[tid] + lhb[tid];
  }
  __syncthreads();
  float qv0 = qqL[lane];
  float qv1 = qqL[64 + lane];
  float lu0 = luw[lane], lu1 = luw[64 + lane];
  float lb = lub[0];
  for (int chunk = 0; chunk < 8; ++chunk) {
    int r0 = row0 + chunk*4;
    #pragma unroll
    for (int i = 0; i < 2; ++i) {
      int idx = tid + i*256;
      rows[idx >> 7][idx & 127] = hmid[(size_t)r0*HIDD + idx];
    }
    __syncthreads();
    const float* R = rows[w];
    float d0 = 0.f, d1 = 0.f;
    #pragma unroll 4
    for (int k = 0; k < HIDD; ++k) {
      float rv = R[k];
      d0 += rv*lhT[k*129 + lane];
      d1 += rv*lhT[k*129 + 64 + lane];
    }
    float t0 = tanhf(d0 + qv0);
    float t1 = tanhf(d1 + qv1);
    float ap = t0*lu0 + t1*lu1;
    #pragma unroll
    for (int off = 32; off > 0; off >>= 1) ap += __shfl_xor(ap, off, 64);
    float a = 1.f/(1.f+expf(-(ap + lb)));
    float o0 = R[lane]     *(1.f+a);
    float o1 = R[64 + lane]*(1.f+a);
    int row = r0 + w, rr = chunk*4 + w;
    hstate[(size_t)row*HIDD + lane]      = o0;
    hstate[(size_t)row*HIDD + 64 + lane] = o1;
    if (outh) {
      outh[(size_t)row*HIDD + lane]      = o0;
      outh[(size_t)row*HIDD + 64 + lane] = o1;
    }
    otile[lane][rr]      = o0;
    otile[64 + lane][rr] = o1;
    __syncthreads();
  }
  // transposed hidden_seq write: out[h][t*BSZ + row0 + rr]
  #pragma unroll
  for (int i = 0; i < 16; ++i) {
    int idx = tid + i*256;
    int h = idx >> 5, rr = idx & 31;
    out[(size_t)h*(TT*(size_t)BSZ) + (size_t)t*BSZ + row0 + rr] = otile[h][rr];
  }
}

extern "C" void kernel_launch(void* const* d_in, const int* in_sizes, int n_in,
                              void* d_out, int out_size, void* d_ws, size_t ws_size,
                              hipStream_t stream)
{
  const float* x = (const float*)d_in[0];
  GP gp;
  int wIdx[8], aIdx[8], bIdx[4];
  // setup_inputs() dict order interleaves b_g per gate group.
  bool dictOrder = (in_sizes[5] == HIDD);
  if (dictOrder) {
    for (int g = 0; g < 4; ++g) {
      int base = 1 + 5*g;
      wIdx[g]   = base;     aIdx[g]   = base + 1;   // W-side GAT
      wIdx[4+g] = base + 2; aIdx[4+g] = base + 3;   // U-side GAT
      bIdx[g]   = base + 4;
    }
  } else {
    for (int g = 0; g < 4; ++g) {
      int base = 1 + 4*g;
      wIdx[g]   = base;     aIdx[g]   = base + 1;
      wIdx[4+g] = base + 2; aIdx[4+g] = base + 3;
      bIdx[g]   = 17 + g;
    }
  }
  for (int s = 0; s < 8; ++s) {
    gp.W[s] = (const float*)d_in[wIdx[s]];
    gp.A[s] = (const float*)d_in[aIdx[s]];
  }
  const float* bi  = (const float*)d_in[bIdx[0]];
  const float* bf  = (const float*)d_in[bIdx[1]];
  const float* bc  = (const float*)d_in[bIdx[2]];
  const float* bo  = (const float*)d_in[bIdx[3]];
  const float* pw  = (const float*)d_in[21];
  const float* pb  = (const float*)d_in[22];
  const float* lhw = (const float*)d_in[23];
  const float* lhb = (const float*)d_in[24];
  const float* lqw = (const float*)d_in[25];
  const float* lqb = (const float*)d_in[26];
  const float* luw = (const float*)d_in[27];
  const float* lub = (const float*)d_in[28];

  float* ws = (float*)d_ws;
  const size_t S = (size_t)BSZ*HIDD;       // 1048576
  float* hW     = ws;                      // 8*S
  float* gat    = hW + 8*S;                // 8*S
  float* hstate = gat + 8*S;               // S
  float* cstate = hstate + S;              // S
  float* hmid   = cstate + S;              // S
  uint4* WfH    = (uint4*)(hmid + S);      // 8*2048*16B = 256 KB
  uint4* WfL    = WfH + 8*2048;            // 256 KB
  float* out = (float*)d_out;
  const size_t off = (size_t)HIDD * (size_t)TT * (size_t)BSZ;  // 16777216

  hipMemsetAsync(hstate, 0, S*sizeof(float), stream);
  hipMemsetAsync(cstate, 0, S*sizeof(float), stream);
  k0_convw<<<8, 256, 0, stream>>>(gp, WfH, WfL);

  for (int t = 0; t < TT; ++t) {
    bool last = (t == TT - 1);
    k1_gemm<<<dim3(64, 8), 256, 0, stream>>>(x, hstate, gp, WfH, WfL, hW, t);
    k2_attn<<<dim3(NB, 8, 2), 256, 0, stream>>>(hW, gp, gat);
    k3_gates<<<1024, 256, 0, stream>>>((const float4*)gat, (const float4*)bi,
        (const float4*)bf, (const float4*)bc, (const float4*)bo,
        (float4*)cstate, (float4*)hmid,
        last ? (float4*)(out + off + S) : (float4*)nullptr);
    k5_fatt<<<256, 256, 0, stream>>>(hmid, pw, pb, lqw, lqb, lhb, lhw, luw, lub,
        hstate, out, t, last ? (out + off) : nullptr);
  }
}

// Round 7
// 1624.896 us; speedup vs baseline: 3.2509x; 1.0328x over previous
//
#include <hip/hip_runtime.h>
#include <cstdint>
#include <cstddef>

#define NN   256      // nodes
#define HIDD 128      // hidden
#define NB   32       // graphs per batch
#define TT   16       // timesteps
#define BSZ  (NB*NN)  // 8192 rows

struct GP {
  const float* W[8];  // s=0..3: Wi,Wf,Wc,Wo ; s=4..7: Ui,Uf,Uc,Uo
  const float* A[8];  // matching a-vectors (256,)
};

typedef __attribute__((ext_vector_type(8))) short bf16x8;
typedef __attribute__((ext_vector_type(4))) float f32x4;
typedef _Float16 f16x8 __attribute__((ext_vector_type(8)));

__device__ __forceinline__ uint16_t bf16rn(float f) {
  uint32_t u = __float_as_uint(f);
  uint32_t r = u + 0x7fffu + ((u >> 16) & 1u);
  return (uint16_t)(r >> 16);
}
__device__ __forceinline__ float bf16f(uint16_t h) {
  return __uint_as_float((uint32_t)h << 16);
}
__device__ __forceinline__ uint16_t f16b(float f) {
  union { _Float16 h; uint16_t u; } cv;
  cv.h = (_Float16)f;
  return cv.u;
}

// ---------------- K0: pre-convert W[s] to fragment-ordered bf16 hi/lo ----------------
__global__ __launch_bounds__(256) void k0_convw(GP gp, uint4* __restrict__ WfH,
    uint4* __restrict__ WfL)
{
  const int s = blockIdx.x;
  const float* __restrict__ W = gp.W[s];
  const int tid = threadIdx.x;
  #pragma unroll
  for (int it = 0; it < 8; ++it) {
    int f = it*256 + tid;               // 0..2047
    int cf = f >> 8, ks = (f >> 6) & 3, l = f & 63;
    int col = cf*16 + (l & 15);
    int kbase = (ks*4 + (l >> 4))*8;
    float v[8];
    #pragma unroll
    for (int j = 0; j < 8; ++j) v[j] = W[(kbase + j)*HIDD + col];
    uint32_t uh[4], ul[4];
    #pragma unroll
    for (int j = 0; j < 4; ++j) {
      uint16_t h0 = bf16rn(v[2*j]), h1 = bf16rn(v[2*j+1]);
      uint16_t l0 = bf16rn(v[2*j]   - bf16f(h0));
      uint16_t l1 = bf16rn(v[2*j+1] - bf16f(h1));
      uh[j] = (uint32_t)h0 | ((uint32_t)h1 << 16);
      ul[j] = (uint32_t)l0 | ((uint32_t)l1 << 16);
    }
    WfH[s*2048 + f] = make_uint4(uh[0], uh[1], uh[2], uh[3]);
    WfL[s*2048 + f] = make_uint4(ul[0], ul[1], ul[2], ul[3]);
  }
}

// ---------------- K0b: Wa[s][k] = sum_c W[k][c]*a{1,2}[c] ----------------
__global__ __launch_bounds__(128) void k0_wa(GP gp, float* __restrict__ Wa)
{
  const int s = blockIdx.x, k = threadIdx.x;
  const float* __restrict__ W = gp.W[s];
  const float* __restrict__ A = gp.A[s];
  float d1 = 0.f, d2 = 0.f;
  #pragma unroll 4
  for (int c = 0; c < HIDD; ++c) {
    float wv = W[k*HIDD + c];
    d1 += wv*A[c];
    d2 += wv*A[HIDD + c];
  }
  Wa[s*256 + k]       = d1;
  Wa[s*256 + 128 + k] = d2;
}

// ---------------- K1: src_s @ W_s -> H fragments (fp16) + f1/f2 ----------------
// H-fragment tile per (t-gate, b): 4096 uint4. Entry
//   f = ((kc*2+ks)*8 + cf)*64 + l  holds h[j][col], col = cf*16+(l&15),
//   j = kc*64 + ks*32 + (l>>4)*8 + 0..7   (fp16).
__global__ __launch_bounds__(256) void k1_gemm(const float* __restrict__ x,
    const float* __restrict__ hstate, const uint4* __restrict__ WfH,
    const uint4* __restrict__ WfL, const float* __restrict__ Wa,
    uint4* __restrict__ HfO, float* __restrict__ f12,
    int sBase, int syMask, int syShift, int wside, int tArg)
{
  const int sy = blockIdx.y;
  const int s = sBase + (sy & syMask);
  const int t = wside ? (sy >> syShift) : tArg;
  const int tIdx = wside ? (t*4 + (s - sBase)) : (s - sBase);
  const int row0 = blockIdx.x * 128;
  const int b = row0 >> 8;
  const int kcl = (row0 >> 7) & 1;
  const int tid = threadIdx.x, lane = tid & 63, w = tid >> 6;
  __shared__ uint4 AH[128*16];   // 32 KB; reused as Th (fp16 transpose) after MFMA
  __shared__ uint4 AL[128*16];   // 32 KB
  __shared__ float red1[2][128], red2[2][128];

  // stage A rows hi/lo (16B-block XOR swizzle by row&7)
  #pragma unroll
  for (int it = 0; it < 8; ++it) {
    int linear = it*256 + tid;
    int r = linear >> 4, blk = linear & 15;
    const float4* p = (s < 4)
      ? reinterpret_cast<const float4*>(x + (size_t)(row0 + r)*(TT*HIDD) + (size_t)t*HIDD)
      : reinterpret_cast<const float4*>(hstate + (size_t)(row0 + r)*HIDD);
    float4 v0 = p[blk*2], v1 = p[blk*2 + 1];
    float vv[8] = {v0.x, v0.y, v0.z, v0.w, v1.x, v1.y, v1.z, v1.w};
    uint32_t uh[4], ul[4];
    #pragma unroll
    for (int j = 0; j < 4; ++j) {
      uint16_t h0 = bf16rn(vv[2*j]), h1 = bf16rn(vv[2*j+1]);
      uint16_t l0 = bf16rn(vv[2*j]   - bf16f(h0));
      uint16_t l1 = bf16rn(vv[2*j+1] - bf16f(h1));
      uh[j] = (uint32_t)h0 | ((uint32_t)h1 << 16);
      ul[j] = (uint32_t)l0 | ((uint32_t)l1 << 16);
    }
    int dst = r*16 + (blk ^ (r & 7));
    AH[dst] = make_uint4(uh[0], uh[1], uh[2], uh[3]);
    AL[dst] = make_uint4(ul[0], ul[1], ul[2], ul[3]);
  }
  __syncthreads();

  // f1/f2 partials: f = src . Wa  (row = tid&127, k-half = tid>>7)
  {
    const int row = tid & 127, kh = tid >> 7;
    const float* __restrict__ wa = Wa + s*256;
    float d1 = 0.f, d2 = 0.f;
    #pragma unroll
    for (int bb = 0; bb < 8; ++bb) {
      int bi = kh*8 + bb;
      uint4 vh = AH[row*16 + (bi ^ (row & 7))];
      uint4 vl = AL[row*16 + (bi ^ (row & 7))];
      #pragma unroll
      for (int j = 0; j < 4; ++j) {
        uint32_t uh = (&vh.x)[j], ul2 = (&vl.x)[j];
        float e0 = __uint_as_float(uh << 16) + __uint_as_float(ul2 << 16);
        float e1 = __uint_as_float(uh & 0xffff0000u) + __uint_as_float(ul2 & 0xffff0000u);
        int k0 = bi*8 + j*2;
        d1 += e0*wa[k0]     + e1*wa[k0+1];
        d2 += e0*wa[128+k0] + e1*wa[128+k0+1];
      }
    }
    red1[kh][row] = d1; red2[kh][row] = d2;
  }
  // MFMA A-fragment register loads
  const int kg = lane >> 4;
  bf16x8 ah[2][4], al[2][4];
  #pragma unroll
  for (int r = 0; r < 2; ++r) {
    int i = w*32 + r*16 + (lane & 15);
    #pragma unroll
    for (int ks = 0; ks < 4; ++ks) {
      int blk = (ks*4 + kg) ^ (i & 7);
      ah[r][ks] = *reinterpret_cast<const bf16x8*>(&AH[i*16 + blk]);
      al[r][ks] = *reinterpret_cast<const bf16x8*>(&AL[i*16 + blk]);
    }
  }
  __syncthreads();
  if (tid < 128) {
    float* fb = f12 + (size_t)tIdx*2*BSZ;
    fb[row0 + tid]       = red1[0][tid] + red1[1][tid];
    fb[BSZ + row0 + tid] = red2[0][tid] + red2[1][tid];
  }

  // MFMA main loop (split bf16: hh + lh + hl)
  f32x4 acc[2][8];
  #pragma unroll
  for (int r = 0; r < 2; ++r)
    #pragma unroll
    for (int c = 0; c < 8; ++c)
      acc[r][c] = (f32x4){0.f, 0.f, 0.f, 0.f};
  const uint4* __restrict__ BH = WfH + s*2048;
  const uint4* __restrict__ BL = WfL + s*2048;
  #pragma unroll
  for (int cf = 0; cf < 8; ++cf) {
    bf16x8 bh[4], bl[4];
    #pragma unroll
    for (int ks = 0; ks < 4; ++ks) {
      bh[ks] = *reinterpret_cast<const bf16x8*>(&BH[(cf*4 + ks)*64 + lane]);
      bl[ks] = *reinterpret_cast<const bf16x8*>(&BL[(cf*4 + ks)*64 + lane]);
    }
    #pragma unroll
    for (int ks = 0; ks < 4; ++ks) {
      #pragma unroll
      for (int r = 0; r < 2; ++r) {
        acc[r][cf] = __builtin_amdgcn_mfma_f32_16x16x32_bf16(ah[r][ks], bh[ks], acc[r][cf], 0, 0, 0);
        acc[r][cf] = __builtin_amdgcn_mfma_f32_16x16x32_bf16(al[r][ks], bh[ks], acc[r][cf], 0, 0, 0);
        acc[r][cf] = __builtin_amdgcn_mfma_f32_16x16x32_bf16(ah[r][ks], bl[ks], acc[r][cf], 0, 0, 0);
      }
    }
  }

  // transpose acc -> Th (alias AH): [col][128 local rows] fp16,
  // 16B-block (8 rows) XOR swizzle by col&7
  char* ThB = reinterpret_cast<char*>(AH);
  #pragma unroll
  for (int r = 0; r < 2; ++r) {
    int jlb = w*32 + r*16 + (lane >> 4)*4;
    #pragma unroll
    for (int cf = 0; cf < 8; ++cf) {
      int col = cf*16 + (lane & 15);
      int off = col*256 + (((jlb >> 3) ^ (col & 7)) << 4) + ((lane >> 4) & 1)*8;
      uint16_t hh[4];
      #pragma unroll
      for (int ii = 0; ii < 4; ++ii) hh[ii] = f16b(acc[r][cf][ii]);
      *reinterpret_cast<uint2*>(ThB + off) =
          make_uint2((uint32_t)hh[0] | ((uint32_t)hh[1] << 16),
                     (uint32_t)hh[2] | ((uint32_t)hh[3] << 16));
    }
  }
  __syncthreads();
  // fragment global stores (this block covers kc = kcl*2 + {0,1})
  uint4* __restrict__ Hf = HfO + (size_t)(tIdx*NB + b)*4096;
  #pragma unroll
  for (int it = 0; it < 8; ++it) {
    int fl = it*256 + tid;
    int l2 = fl & 63, cf = (fl >> 6) & 7, ks = (fl >> 9) & 1, kchalf = fl >> 10;
    int col = cf*16 + (l2 & 15);
    int jl = kchalf*64 + ks*32 + (l2 >> 4)*8;
    int soff = col*256 + (((jl >> 3) ^ (col & 7)) << 4);
    int kc = kcl*2 + kchalf;
    size_t fg = (size_t)((kc*2 + ks)*8 + cf)*64 + l2;
    Hf[fg] = *reinterpret_cast<const uint4*>(ThB + soff);
  }
}

// ---------------- K2: gat[s] = elu(softmax(leaky(f1_i+f2_j)) @ h), fp16 PV ----------------
__global__ __launch_bounds__(256) void k2_attn(
    const uint4* __restrict__ HfW, const uint4* __restrict__ HfU,
    const float* __restrict__ f12W, const float* __restrict__ f12U,
    float* __restrict__ gat, int t, int pre)
{
  const int s = blockIdx.y;
  const int b = blockIdx.x;
  const int roff = blockIdx.z * 128;
  const int tid = threadIdx.x, lane = tid & 63, w = tid >> 6;
  const int rl = tid & 127, half = tid >> 7;
  __shared__ __align__(16) float f2L[NN];
  __shared__ __align__(16) float sums[256];
  __shared__ __align__(16) uint16_t Pb[128*64];   // 16 KB fp16 [row][64k] swizzled
  const uint4 *BH;
  const float* fb;
  if (pre && s < 4) {
    size_t tg = (size_t)(t*4 + s);
    BH = HfW + (tg*NB + b)*4096;
    fb = f12W + tg*2*BSZ;
  } else {
    size_t tg = (size_t)(s - (pre ? 4 : 0));
    BH = HfU + (tg*NB + b)*4096;
    fb = f12U + tg*2*BSZ;
  }
  f2L[tid] = fb[BSZ + b*NN + tid];
  const float f1v = fb[b*NN + roff + rl];

  const float4* f24 = reinterpret_cast<const float4*>(f2L);
  float ssum = 0.f;
  f32x4 acc[2][8];
  #pragma unroll
  for (int r = 0; r < 2; ++r)
    #pragma unroll
    for (int c = 0; c < 8; ++c)
      acc[r][c] = (f32x4){0.f, 0.f, 0.f, 0.f};
  char* PbB = reinterpret_cast<char*>(Pb);
  const int kg = lane >> 4;

  for (int kc = 0; kc < 4; ++kc) {
    __syncthreads();
    // P-gen (unnormalized, single pass, fp16)
    #pragma unroll
    for (int bb = 0; bb < 4; ++bb) {
      int blk = half*4 + bb;
      float4 va = f24[kc*16 + blk*2];
      float4 vb = f24[kc*16 + blk*2 + 1];
      float e0 = f1v + va.x; e0 = e0 > 0.f ? e0 : 0.01f*e0;
      float e1 = f1v + va.y; e1 = e1 > 0.f ? e1 : 0.01f*e1;
      float e2 = f1v + va.z; e2 = e2 > 0.f ? e2 : 0.01f*e2;
      float e3 = f1v + va.w; e3 = e3 > 0.f ? e3 : 0.01f*e3;
      float e4 = f1v + vb.x; e4 = e4 > 0.f ? e4 : 0.01f*e4;
      float e5 = f1v + vb.y; e5 = e5 > 0.f ? e5 : 0.01f*e5;
      float e6 = f1v + vb.z; e6 = e6 > 0.f ? e6 : 0.01f*e6;
      float e7 = f1v + vb.w; e7 = e7 > 0.f ? e7 : 0.01f*e7;
      float p0 = expf(e0), p1 = expf(e1), p2 = expf(e2), p3 = expf(e3);
      float p4 = expf(e4), p5 = expf(e5), p6 = expf(e6), p7 = expf(e7);
      ssum += (p0 + p1) + (p2 + p3) + ((p4 + p5) + (p6 + p7));
      uint32_t u0 = (uint32_t)f16b(p0) | ((uint32_t)f16b(p1) << 16);
      uint32_t u1 = (uint32_t)f16b(p2) | ((uint32_t)f16b(p3) << 16);
      uint32_t u2 = (uint32_t)f16b(p4) | ((uint32_t)f16b(p5) << 16);
      uint32_t u3 = (uint32_t)f16b(p6) | ((uint32_t)f16b(p7) << 16);
      *reinterpret_cast<uint4*>(PbB + rl*128 + ((blk ^ (rl & 7)) << 4)) =
          make_uint4(u0, u1, u2, u3);
    }
    __syncthreads();
    #pragma unroll
    for (int ks = 0; ks < 2; ++ks) {
      f16x8 af[2];
      #pragma unroll
      for (int r = 0; r < 2; ++r) {
        int i = w*32 + r*16 + (lane & 15);
        int blk = (ks*4 + kg) ^ (i & 7);
        af[r] = *reinterpret_cast<const f16x8*>(PbB + i*128 + blk*16);
      }
      #pragma unroll
      for (int c = 0; c < 8; ++c) {
        size_t fg = (size_t)((kc*2 + ks)*8 + c)*64 + lane;
        f16x8 bh = *reinterpret_cast<const f16x8*>(&BH[fg]);
        #pragma unroll
        for (int r = 0; r < 2; ++r)
          acc[r][c] = __builtin_amdgcn_mfma_f32_16x16x32_f16(af[r], bh, acc[r][c], 0, 0, 0);
      }
    }
  }
  sums[tid] = ssum;
  __syncthreads();

  float* __restrict__ gout = gat + ((size_t)s*BSZ + (size_t)b*NN)*HIDD;
  #pragma unroll
  for (int r = 0; r < 2; ++r) {
    int lrb = w*32 + r*16 + (lane >> 4)*4;
    int row = roff + lrb;
    #pragma unroll
    for (int ii = 0; ii < 4; ++ii) {
      float rs = 1.f / (sums[lrb + ii] + sums[128 + lrb + ii]);
      #pragma unroll
      for (int c = 0; c < 8; ++c) {
        int col = c*16 + (lane & 15);
        float v = acc[r][c][ii] * rs;
        v = v > 0.f ? v : expm1f(v);
        gout[(size_t)(row + ii)*HIDD + col] = v;
      }
    }
  }
}

// ---------------- K3: LSTM gate combine (float4) ----------------
__global__ __launch_bounds__(256) void k3_gates(const float4* __restrict__ gat4,
    const float4* __restrict__ bi4, const float4* __restrict__ bf4,
    const float4* __restrict__ bc4, const float4* __restrict__ bo4,
    float4* __restrict__ c4, float4* __restrict__ hm4, float4* __restrict__ outc4)
{
  const size_t S4 = (size_t)BSZ*HIDD/4;
  size_t idx = (size_t)blockIdx.x*256 + threadIdx.x;
  int hc = (int)(idx & 31);
  float4 gi = gat4[idx], gf = gat4[S4+idx], gc = gat4[2*S4+idx], go = gat4[3*S4+idx];
  float4 ui = gat4[4*S4+idx], uf = gat4[5*S4+idx], uc = gat4[6*S4+idx], uo = gat4[7*S4+idx];
  float4 Bi = bi4[hc], Bf = bf4[hc], Bc = bc4[hc], Bo = bo4[hc];
  float4 cv = c4[idx], hv, cn;
  #pragma unroll
  for (int j = 0; j < 4; ++j) {
    float xi = (&gi.x)[j] + (&ui.x)[j] + (&Bi.x)[j];
    float xf = (&gf.x)[j] + (&uf.x)[j] + (&Bf.x)[j];
    float xc = (&gc.x)[j] + (&uc.x)[j] + (&Bc.x)[j];
    float xo = (&go.x)[j] + (&uo.x)[j] + (&Bo.x)[j];
    float it = 1.f/(1.f+expf(-xi));
    float ft = 1.f/(1.f+expf(-xf));
    float gt = tanhf(xc);
    float ot = 1.f/(1.f+expf(-xo));
    float c = ft*(&cv.x)[j] + it*gt;
    (&cn.x)[j] = c;
    (&hv.x)[j] = ot*tanhf(c);
  }
  c4[idx] = cn;
  hm4[idx] = hv;
  if (outc4) outc4[idx] = cn;
}

// ---------------- K5: pool + qq + fatt + residual + transposed seq write ----------------
__global__ __launch_bounds__(256) void k5_fatt(const float* __restrict__ hmid,
    const float* __restrict__ pw, const float* __restrict__ pb,
    const float* __restrict__ lqw, const float* __restrict__ lqb,
    const float* __restrict__ lhb, const float* __restrict__ lhw,
    const float* __restrict__ luw, const float* __restrict__ lub,
    float* __restrict__ hstate, float* __restrict__ out, int t,
    float* __restrict__ outh)
{
  const int tid = threadIdx.x, lane = tid & 63, w = tid >> 6;
  const int row0 = blockIdx.x * 32;
  const int b = row0 >> 8;
  __shared__ float lhT[HIDD*129];
  __shared__ float rows[4][HIDD];
  __shared__ float otile[HIDD][33];
  __shared__ float qsum[256];
  __shared__ float qqL[HIDD];
  #pragma unroll
  for (int i = 0; i < 64; ++i) {
    int idx = tid + i*256;
    int hp = idx >> 7, k = idx & 127;
    lhT[k*129 + hp] = lhw[idx];
  }
  {
    const int h = tid & 127, half = tid >> 7;
    const float* hb = hmid + (size_t)b*NN*HIDD;
    float qacc = 0.f;
    #pragma unroll 4
    for (int n = half*128; n < half*128 + 128; ++n)
      qacc += hb[(size_t)n*HIDD + h] * pw[n];
    qsum[tid] = qacc;
  }
  __syncthreads();
  if (tid < 128) {
    float q = fmaxf(qsum[tid] + qsum[128 + tid] + pb[0], 0.f);
    qsum[tid] = q;
  }
  __syncthreads();
  if (tid < 128) {
    float acc = 0.f;
    #pragma unroll 4
    for (int k = 0; k < HIDD; ++k) acc += qsum[k]*lqw[tid*HIDD + k];
    qqL[tid] = acc + lqb[tid] + lhb[tid];
  }
  __syncthreads();
  float qv0 = qqL[lane];
  float qv1 = qqL[64 + lane];
  float lu0 = luw[lane], lu1 = luw[64 + lane];
  float lb = lub[0];
  for (int chunk = 0; chunk < 8; ++chunk) {
    int r0 = row0 + chunk*4;
    #pragma unroll
    for (int i = 0; i < 2; ++i) {
      int idx = tid + i*256;
      rows[idx >> 7][idx & 127] = hmid[(size_t)r0*HIDD + idx];
    }
    __syncthreads();
    const float* R = rows[w];
    float d0 = 0.f, d1 = 0.f;
    #pragma unroll 4
    for (int k = 0; k < HIDD; ++k) {
      float rv = R[k];
      d0 += rv*lhT[k*129 + lane];
      d1 += rv*lhT[k*129 + 64 + lane];
    }
    float t0 = tanhf(d0 + qv0);
    float t1 = tanhf(d1 + qv1);
    float ap = t0*lu0 + t1*lu1;
    #pragma unroll
    for (int off = 32; off > 0; off >>= 1) ap += __shfl_xor(ap, off, 64);
    float a = 1.f/(1.f+expf(-(ap + lb)));
    float o0 = R[lane]     *(1.f+a);
    float o1 = R[64 + lane]*(1.f+a);
    int row = r0 + w, rr = chunk*4 + w;
    hstate[(size_t)row*HIDD + lane]      = o0;
    hstate[(size_t)row*HIDD + 64 + lane] = o1;
    if (outh) {
      outh[(size_t)row*HIDD + lane]      = o0;
      outh[(size_t)row*HIDD + 64 + lane] = o1;
    }
    otile[lane][rr]      = o0;
    otile[64 + lane][rr] = o1;
    __syncthreads();
  }
  #pragma unroll
  for (int i = 0; i < 16; ++i) {
    int idx = tid + i*256;
    int h = idx >> 5, rr = idx & 31;
    out[(size_t)h*(TT*(size_t)BSZ) + (size_t)t*BSZ + row0 + rr] = otile[h][rr];
  }
}

extern "C" void kernel_launch(void* const* d_in, const int* in_sizes, int n_in,
                              void* d_out, int out_size, void* d_ws, size_t ws_size,
                              hipStream_t stream)
{
  const float* x = (const float*)d_in[0];
  GP gp;
  int wIdx[8], aIdx[8], bIdx[4];
  bool dictOrder = (in_sizes[5] == HIDD);
  if (dictOrder) {
    for (int g = 0; g < 4; ++g) {
      int base = 1 + 5*g;
      wIdx[g]   = base;     aIdx[g]   = base + 1;
      wIdx[4+g] = base + 2; aIdx[4+g] = base + 3;
      bIdx[g]   = base + 4;
    }
  } else {
    for (int g = 0; g < 4; ++g) {
      int base = 1 + 4*g;
      wIdx[g]   = base;     aIdx[g]   = base + 1;
      wIdx[4+g] = base + 2; aIdx[4+g] = base + 3;
      bIdx[g]   = 17 + g;
    }
  }
  for (int s = 0; s < 8; ++s) {
    gp.W[s] = (const float*)d_in[wIdx[s]];
    gp.A[s] = (const float*)d_in[aIdx[s]];
  }
  const float* bi  = (const float*)d_in[bIdx[0]];
  const float* bf  = (const float*)d_in[bIdx[1]];
  const float* bc  = (const float*)d_in[bIdx[2]];
  const float* bo  = (const float*)d_in[bIdx[3]];
  const float* pw  = (const float*)d_in[21];
  const float* pb  = (const float*)d_in[22];
  const float* lhw = (const float*)d_in[23];
  const float* lhb = (const float*)d_in[24];
  const float* lqw = (const float*)d_in[25];
  const float* lqb = (const float*)d_in[26];
  const float* luw = (const float*)d_in[27];
  const float* lub = (const float*)d_in[28];

  const size_t S = (size_t)BSZ*HIDD;       // 1048576
  float* ws = (float*)d_ws;
  float* gat    = ws;                      // 8*S floats (32 MB)
  float* hstate = gat + 8*S;               // S
  float* cstate = hstate + S;              // S
  float* hmid   = cstate + S;              // S
  float* f12U   = hmid + S;                // 8*2*BSZ = 131072
  float* Wa     = f12U + 8*2*BSZ;          // 2048
  uint4* WfH    = (uint4*)(Wa + 2048);     // 16384 uint4 (256 KB)
  uint4* WfL    = WfH + 8*2048;            // 256 KB
  uint4* HfU    = WfL + 8*2048;            // 8*NB*4096 uint4 = 16 MB
  uint4* HfW    = HfU + (size_t)8*NB*4096;    // 64*NB*4096 uint4 = 128 MB
  float* f12W   = (float*)(HfW + (size_t)64*NB*4096);  // 64*2*BSZ = 4 MB
  // total with prepass ~193 MB
  bool pre = ws_size >= (size_t)205*1024*1024;

  float* out = (float*)d_out;
  const size_t off = (size_t)HIDD * (size_t)TT * (size_t)BSZ;  // 16777216

  hipMemsetAsync(hstate, 0, S*sizeof(float), stream);
  hipMemsetAsync(cstate, 0, S*sizeof(float), stream);
  k0_convw<<<8, 256, 0, stream>>>(gp, WfH, WfL);
  k0_wa<<<8, 128, 0, stream>>>(gp, Wa);

  if (pre) {
    // all W-side GEMMs for all t in one launch: sy = t*4 + s
    k1_gemm<<<dim3(64, 64), 256, 0, stream>>>(x, hstate, WfH, WfL, Wa,
        HfW, f12W, 0, 3, 2, 1, 0);
  }

  for (int t = 0; t < TT; ++t) {
    bool last = (t == TT - 1);
    if (pre) {
      k1_gemm<<<dim3(64, 4), 256, 0, stream>>>(x, hstate, WfH, WfL, Wa,
          HfU, f12U, 4, 3, 2, 0, t);
      k2_attn<<<dim3(NB, 8, 2), 256, 0, stream>>>(HfW, HfU, f12W, f12U, gat, t, 1);
    } else {
      k1_gemm<<<dim3(64, 8), 256, 0, stream>>>(x, hstate, WfH, WfL, Wa,
          HfU, f12U, 0, 7, 3, 0, t);
      k2_attn<<<dim3(NB, 8, 2), 256, 0, stream>>>(HfU, HfU, f12U, f12U, gat, t, 0);
    }
    k3_gates<<<1024, 256, 0, stream>>>((const float4*)gat, (const float4*)bi,
        (const float4*)bf, (const float4*)bc, (const float4*)bo,
        (float4*)cstate, (float4*)hmid,
        last ? (float4*)(out + off + S) : (float4*)nullptr);
    k5_fatt<<<256, 256, 0, stream>>>(hmid, pw, pb, lqw, lqb, lhb, lhw, luw, lub,
        hstate, out, t, last ? (out + off) : nullptr);
  }
}

// Round 8
// 1604.676 us; speedup vs baseline: 3.2918x; 1.0126x over previous
//
#include <hip/hip_runtime.h>
#include <cstdint>
#include <cstddef>

#define NN   256      // nodes
#define HIDD 128      // hidden
#define NB   32       // graphs per batch
#define TT   16       // timesteps
#define BSZ  (NB*NN)  // 8192 rows

struct GP {
  const float* W[8];  // s=0..3: Wi,Wf,Wc,Wo ; s=4..7: Ui,Uf,Uc,Uo
  const float* A[8];  // matching a-vectors (256,)
};

typedef __attribute__((ext_vector_type(8))) short bf16x8;
typedef __attribute__((ext_vector_type(4))) float f32x4;
typedef _Float16 f16x8 __attribute__((ext_vector_type(8)));

__device__ __forceinline__ uint16_t bf16rn(float f) {
  uint32_t u = __float_as_uint(f);
  uint32_t r = u + 0x7fffu + ((u >> 16) & 1u);
  return (uint16_t)(r >> 16);
}
__device__ __forceinline__ float bf16f(uint16_t h) {
  return __uint_as_float((uint32_t)h << 16);
}
__device__ __forceinline__ uint16_t f16b(float f) {
  union { _Float16 h; uint16_t u; } cv;
  cv.h = (_Float16)f;
  return cv.u;
}

// ---------------- K0: pre-convert W[s] to fragment-ordered bf16 hi/lo ----------------
__global__ __launch_bounds__(256) void k0_convw(GP gp, uint4* __restrict__ WfH,
    uint4* __restrict__ WfL)
{
  const int s = blockIdx.x;
  const float* __restrict__ W = gp.W[s];
  const int tid = threadIdx.x;
  #pragma unroll
  for (int it = 0; it < 8; ++it) {
    int f = it*256 + tid;               // 0..2047
    int cf = f >> 8, ks = (f >> 6) & 3, l = f & 63;
    int col = cf*16 + (l & 15);
    int kbase = (ks*4 + (l >> 4))*8;
    float v[8];
    #pragma unroll
    for (int j = 0; j < 8; ++j) v[j] = W[(kbase + j)*HIDD + col];
    uint32_t uh[4], ul[4];
    #pragma unroll
    for (int j = 0; j < 4; ++j) {
      uint16_t h0 = bf16rn(v[2*j]), h1 = bf16rn(v[2*j+1]);
      uint16_t l0 = bf16rn(v[2*j]   - bf16f(h0));
      uint16_t l1 = bf16rn(v[2*j+1] - bf16f(h1));
      uh[j] = (uint32_t)h0 | ((uint32_t)h1 << 16);
      ul[j] = (uint32_t)l0 | ((uint32_t)l1 << 16);
    }
    WfH[s*2048 + f] = make_uint4(uh[0], uh[1], uh[2], uh[3]);
    WfL[s*2048 + f] = make_uint4(ul[0], ul[1], ul[2], ul[3]);
  }
}

// ---------------- K0b: Wa[s][k] = sum_c W[k][c]*a{1,2}[c] ----------------
__global__ __launch_bounds__(128) void k0_wa(GP gp, float* __restrict__ Wa)
{
  const int s = blockIdx.x, k = threadIdx.x;
  const float* __restrict__ W = gp.W[s];
  const float* __restrict__ A = gp.A[s];
  float d1 = 0.f, d2 = 0.f;
  #pragma unroll 4
  for (int c = 0; c < HIDD; ++c) {
    float wv = W[k*HIDD + c];
    d1 += wv*A[c];
    d2 += wv*A[HIDD + c];
  }
  Wa[s*256 + k]       = d1;
  Wa[s*256 + 128 + k] = d2;
}

// ---------------- K1: src_s @ W_s -> H fragments (fp16) + f1/f2 ----------------
// 64-row tiles. H-fragment tile per (t-gate, b): 4096 uint4.
//   f = ((kc*2+ks)*8 + cf)*64 + l  holds h[j][col], col = cf*16+(l&15),
//   j = kc*64 + ks*32 + (l>>4)*8 + 0..7   (fp16).
__global__ __launch_bounds__(256) void k1_gemm(const float* __restrict__ x,
    const float* __restrict__ hstate, const uint4* __restrict__ WfH,
    const uint4* __restrict__ WfL, const float* __restrict__ Wa,
    uint4* __restrict__ HfO, float* __restrict__ f12,
    int sBase, int syMask, int syShift, int wside, int tArg)
{
  const int sy = blockIdx.y;
  const int s = sBase + (sy & syMask);
  const int t = wside ? (sy >> syShift) : tArg;
  const int tIdx = wside ? (t*4 + (s - sBase)) : (s - sBase);
  const int row0 = blockIdx.x * 64;
  const int b = row0 >> 8;
  const int kc = (row0 >> 6) & 3;
  const int tid = threadIdx.x, lane = tid & 63, w = tid >> 6;
  __shared__ __align__(16) uint4 SH[2048];   // AH=SH[0..1023], AL=SH[1024..2047]; Th overlays
  __shared__ float red1[4][64], red2[4][64];
  uint4* AH = SH;
  uint4* AL = SH + 1024;

  // stage A rows hi/lo bf16 (16B-block XOR swizzle by row&7)
  #pragma unroll
  for (int it = 0; it < 4; ++it) {
    int linear = it*256 + tid;          // 0..1023
    int r = linear >> 4, blk = linear & 15;
    const float4* p = (s < 4)
      ? reinterpret_cast<const float4*>(x + (size_t)(row0 + r)*(TT*HIDD) + (size_t)t*HIDD)
      : reinterpret_cast<const float4*>(hstate + (size_t)(row0 + r)*HIDD);
    float4 v0 = p[blk*2], v1 = p[blk*2 + 1];
    float vv[8] = {v0.x, v0.y, v0.z, v0.w, v1.x, v1.y, v1.z, v1.w};
    uint32_t uh[4], ul[4];
    #pragma unroll
    for (int j = 0; j < 4; ++j) {
      uint16_t h0 = bf16rn(vv[2*j]), h1 = bf16rn(vv[2*j+1]);
      uint16_t l0 = bf16rn(vv[2*j]   - bf16f(h0));
      uint16_t l1 = bf16rn(vv[2*j+1] - bf16f(h1));
      uh[j] = (uint32_t)h0 | ((uint32_t)h1 << 16);
      ul[j] = (uint32_t)l0 | ((uint32_t)l1 << 16);
    }
    int dst = r*16 + (blk ^ (r & 7));
    AH[dst] = make_uint4(uh[0], uh[1], uh[2], uh[3]);
    AL[dst] = make_uint4(ul[0], ul[1], ul[2], ul[3]);
  }
  __syncthreads();

  // f1/f2 partials: f = src . Wa  (row = tid&63, k-quarter = tid>>6)
  {
    const int row = tid & 63, kq = tid >> 6;
    const float* __restrict__ wa = Wa + s*256;
    float d1 = 0.f, d2 = 0.f;
    #pragma unroll
    for (int bb = 0; bb < 4; ++bb) {
      int bi = kq*4 + bb;
      uint4 vh = AH[row*16 + (bi ^ (row & 7))];
      uint4 vl = AL[row*16 + (bi ^ (row & 7))];
      #pragma unroll
      for (int j = 0; j < 4; ++j) {
        uint32_t uh = (&vh.x)[j], ul2 = (&vl.x)[j];
        float e0 = __uint_as_float(uh << 16) + __uint_as_float(ul2 << 16);
        float e1 = __uint_as_float(uh & 0xffff0000u) + __uint_as_float(ul2 & 0xffff0000u);
        int k0 = bi*8 + j*2;
        d1 += e0*wa[k0]     + e1*wa[k0+1];
        d2 += e0*wa[128+k0] + e1*wa[128+k0+1];
      }
    }
    red1[kq][row] = d1; red2[kq][row] = d2;
  }
  // MFMA A-fragment register loads (wave w owns rows w*16..+15)
  const int kg = lane >> 4;
  bf16x8 ah[4], al[4];
  {
    int i = w*16 + (lane & 15);
    #pragma unroll
    for (int ks = 0; ks < 4; ++ks) {
      int blk = (ks*4 + kg) ^ (i & 7);
      ah[ks] = *reinterpret_cast<const bf16x8*>(&AH[i*16 + blk]);
      al[ks] = *reinterpret_cast<const bf16x8*>(&AL[i*16 + blk]);
    }
  }
  __syncthreads();
  if (tid < 64) {
    float* fb = f12 + (size_t)tIdx*2*BSZ;
    fb[row0 + tid]       = red1[0][tid] + red1[1][tid] + red1[2][tid] + red1[3][tid];
    fb[BSZ + row0 + tid] = red2[0][tid] + red2[1][tid] + red2[2][tid] + red2[3][tid];
  }

  // MFMA main loop (split bf16: hh + lh + hl)
  f32x4 acc[8];
  #pragma unroll
  for (int c = 0; c < 8; ++c) acc[c] = (f32x4){0.f, 0.f, 0.f, 0.f};
  const uint4* __restrict__ BH = WfH + s*2048;
  const uint4* __restrict__ BL = WfL + s*2048;
  #pragma unroll
  for (int cf = 0; cf < 8; ++cf) {
    bf16x8 bh[4], bl[4];
    #pragma unroll
    for (int ks = 0; ks < 4; ++ks) {
      bh[ks] = *reinterpret_cast<const bf16x8*>(&BH[(cf*4 + ks)*64 + lane]);
      bl[ks] = *reinterpret_cast<const bf16x8*>(&BL[(cf*4 + ks)*64 + lane]);
    }
    #pragma unroll
    for (int ks = 0; ks < 4; ++ks) {
      acc[cf] = __builtin_amdgcn_mfma_f32_16x16x32_bf16(ah[ks], bh[ks], acc[cf], 0, 0, 0);
      acc[cf] = __builtin_amdgcn_mfma_f32_16x16x32_bf16(al[ks], bh[ks], acc[cf], 0, 0, 0);
      acc[cf] = __builtin_amdgcn_mfma_f32_16x16x32_bf16(ah[ks], bl[ks], acc[cf], 0, 0, 0);
    }
  }

  // transpose acc -> Th (overlays SH): [col][64 jl] fp16, padded stride 144 B/col
  char* ThB = reinterpret_cast<char*>(SH);
  {
    int jlb = w*16 + (lane >> 4)*4;
    #pragma unroll
    for (int cf = 0; cf < 8; ++cf) {
      int col = cf*16 + (lane & 15);
      uint16_t hh[4];
      #pragma unroll
      for (int ii = 0; ii < 4; ++ii) hh[ii] = f16b(acc[cf][ii]);
      *reinterpret_cast<uint2*>(ThB + col*144 + jlb*2) =
          make_uint2((uint32_t)hh[0] | ((uint32_t)hh[1] << 16),
                     (uint32_t)hh[2] | ((uint32_t)hh[3] << 16));
    }
  }
  __syncthreads();
  // fragment global stores (this block covers chunk kc)
  uint4* __restrict__ Hf = HfO + (size_t)(tIdx*NB + b)*4096;
  #pragma unroll
  for (int it = 0; it < 4; ++it) {
    int fl = it*256 + tid;              // 0..1023
    int l2 = fl & 63, cf = (fl >> 6) & 7, ks = fl >> 9;  // ks 0..1
    int col = cf*16 + (l2 & 15);
    int jl = ks*32 + (l2 >> 4)*8;
    uint4 v = *reinterpret_cast<const uint4*>(ThB + col*144 + jl*2);
    size_t fg = (size_t)((kc*2 + ks)*8 + cf)*64 + l2;
    Hf[fg] = v;
  }
}

// ---------------- K2: gat[s] = elu(softmax(leaky(f1_i+f2_j)) @ h), fp16 PV ----------------
// 64-row blocks; grid (NB, 8, 4).
__global__ __launch_bounds__(256) void k2_attn(
    const uint4* __restrict__ HfW, const uint4* __restrict__ HfU,
    const float* __restrict__ f12W, const float* __restrict__ f12U,
    float* __restrict__ gat, int t, int pre)
{
  const int s = blockIdx.y;
  const int b = blockIdx.x;
  const int roff = blockIdx.z * 64;
  const int tid = threadIdx.x, lane = tid & 63, w = tid >> 6;
  const int rl = tid & 63, qh = tid >> 6;     // row-local, j-quarter
  __shared__ __align__(16) float f2L[NN];
  __shared__ __align__(16) float sums[256];
  __shared__ __align__(16) uint16_t Pb[64*64];   // 8 KB fp16 [row][64j] swizzled
  const uint4 *BH;
  const float* fb;
  if (pre && s < 4) {
    size_t tg = (size_t)(t*4 + s);
    BH = HfW + (tg*NB + b)*4096;
    fb = f12W + tg*2*BSZ;
  } else {
    size_t tg = (size_t)(s - (pre ? 4 : 0));
    BH = HfU + (tg*NB + b)*4096;
    fb = f12U + tg*2*BSZ;
  }
  f2L[tid] = fb[BSZ + b*NN + tid];
  const float f1v = fb[b*NN + roff + rl];

  const float4* f24 = reinterpret_cast<const float4*>(f2L);
  float ssum = 0.f;
  f32x4 acc[8];
  #pragma unroll
  for (int c = 0; c < 8; ++c) acc[c] = (f32x4){0.f, 0.f, 0.f, 0.f};
  char* PbB = reinterpret_cast<char*>(Pb);
  const int kg = lane >> 4;

  for (int kc = 0; kc < 4; ++kc) {
    __syncthreads();
    // P-gen: thread covers row rl, j-blocks qh*2 + {0,1}
    #pragma unroll
    for (int bb = 0; bb < 2; ++bb) {
      int blk = qh*2 + bb;
      float4 va = f24[kc*16 + blk*2];
      float4 vb = f24[kc*16 + blk*2 + 1];
      float e0 = f1v + va.x; e0 = e0 > 0.f ? e0 : 0.01f*e0;
      float e1 = f1v + va.y; e1 = e1 > 0.f ? e1 : 0.01f*e1;
      float e2 = f1v + va.z; e2 = e2 > 0.f ? e2 : 0.01f*e2;
      float e3 = f1v + va.w; e3 = e3 > 0.f ? e3 : 0.01f*e3;
      float e4 = f1v + vb.x; e4 = e4 > 0.f ? e4 : 0.01f*e4;
      float e5 = f1v + vb.y; e5 = e5 > 0.f ? e5 : 0.01f*e5;
      float e6 = f1v + vb.z; e6 = e6 > 0.f ? e6 : 0.01f*e6;
      float e7 = f1v + vb.w; e7 = e7 > 0.f ? e7 : 0.01f*e7;
      float p0 = expf(e0), p1 = expf(e1), p2 = expf(e2), p3 = expf(e3);
      float p4 = expf(e4), p5 = expf(e5), p6 = expf(e6), p7 = expf(e7);
      ssum += (p0 + p1) + (p2 + p3) + ((p4 + p5) + (p6 + p7));
      uint32_t u0 = (uint32_t)f16b(p0) | ((uint32_t)f16b(p1) << 16);
      uint32_t u1 = (uint32_t)f16b(p2) | ((uint32_t)f16b(p3) << 16);
      uint32_t u2 = (uint32_t)f16b(p4) | ((uint32_t)f16b(p5) << 16);
      uint32_t u3 = (uint32_t)f16b(p6) | ((uint32_t)f16b(p7) << 16);
      *reinterpret_cast<uint4*>(PbB + rl*128 + ((blk ^ (rl & 7)) << 4)) =
          make_uint4(u0, u1, u2, u3);
    }
    __syncthreads();
    #pragma unroll
    for (int ks = 0; ks < 2; ++ks) {
      int i = w*16 + (lane & 15);
      int blk = (ks*4 + kg) ^ (i & 7);
      f16x8 af = *reinterpret_cast<const f16x8*>(PbB + i*128 + blk*16);
      #pragma unroll
      for (int c = 0; c < 8; ++c) {
        size_t fg = (size_t)((kc*2 + ks)*8 + c)*64 + lane;
        f16x8 bh = *reinterpret_cast<const f16x8*>(&BH[fg]);
        acc[c] = __builtin_amdgcn_mfma_f32_16x16x32_f16(af, bh, acc[c], 0, 0, 0);
      }
    }
  }
  sums[tid] = ssum;
  __syncthreads();

  float* __restrict__ gout = gat + ((size_t)s*BSZ + (size_t)b*NN)*HIDD;
  {
    int lrb = w*16 + (lane >> 4)*4;
    int row = roff + lrb;
    #pragma unroll
    for (int ii = 0; ii < 4; ++ii) {
      float rs = 1.f / (sums[lrb + ii] + sums[64 + lrb + ii] +
                        sums[128 + lrb + ii] + sums[192 + lrb + ii]);
      #pragma unroll
      for (int c = 0; c < 8; ++c) {
        int col = c*16 + (lane & 15);
        float v = acc[c][ii] * rs;
        v = v > 0.f ? v : expm1f(v);
        gout[(size_t)(row + ii)*HIDD + col] = v;
      }
    }
  }
}

// ---------------- K3: LSTM gate combine (float4) + pool partials ----------------
__global__ __launch_bounds__(256) void k3_gates(const float4* __restrict__ gat4,
    const float4* __restrict__ bi4, const float4* __restrict__ bf4,
    const float4* __restrict__ bc4, const float4* __restrict__ bo4,
    float4* __restrict__ c4, float4* __restrict__ hm4, float4* __restrict__ outc4,
    const float* __restrict__ pw, float4* __restrict__ qpart)
{
  const size_t S4 = (size_t)BSZ*HIDD/4;
  const int tid = threadIdx.x;
  size_t idx = (size_t)blockIdx.x*256 + tid;
  int hc = (int)(idx & 31);
  float4 gi = gat4[idx], gf = gat4[S4+idx], gc = gat4[2*S4+idx], go = gat4[3*S4+idx];
  float4 ui = gat4[4*S4+idx], uf = gat4[5*S4+idx], uc = gat4[6*S4+idx], uo = gat4[7*S4+idx];
  float4 Bi = bi4[hc], Bf = bf4[hc], Bc = bc4[hc], Bo = bo4[hc];
  float4 cv = c4[idx], hv, cn;
  #pragma unroll
  for (int j = 0; j < 4; ++j) {
    float xi = (&gi.x)[j] + (&ui.x)[j] + (&Bi.x)[j];
    float xf = (&gf.x)[j] + (&uf.x)[j] + (&Bf.x)[j];
    float xc = (&gc.x)[j] + (&uc.x)[j] + (&Bc.x)[j];
    float xo = (&go.x)[j] + (&uo.x)[j] + (&Bo.x)[j];
    float it = 1.f/(1.f+expf(-xi));
    float ft = 1.f/(1.f+expf(-xf));
    float gt = tanhf(xc);
    float ot = 1.f/(1.f+expf(-xo));
    float c = ft*(&cv.x)[j] + it*gt;
    (&cn.x)[j] = c;
    (&hv.x)[j] = ot*tanhf(c);
  }
  c4[idx] = cn;
  hm4[idx] = hv;
  if (outc4) outc4[idx] = cn;
  // pool partial: block covers 8 rows of one batch
  int row = (int)(idx >> 5);
  float pwv = pw[row & 255];
  __shared__ float4 pp[256];
  pp[tid] = make_float4(hv.x*pwv, hv.y*pwv, hv.z*pwv, hv.w*pwv);
  __syncthreads();
  if (tid < 32) {
    float4 sa = pp[tid];
    #pragma unroll
    for (int k = 1; k < 8; ++k) {
      float4 v = pp[tid + k*32];
      sa.x += v.x; sa.y += v.y; sa.z += v.z; sa.w += v.w;
    }
    qpart[(size_t)blockIdx.x*32 + tid] = sa;
  }
}

// ---------------- K5: qq from partials + fatt + residual + transposed seq write ----------------
__global__ __launch_bounds__(256) void k5_fatt(const float* __restrict__ hmid,
    const float* __restrict__ qpartF, const float* __restrict__ pb,
    const float* __restrict__ lqw, const float* __restrict__ lqb,
    const float* __restrict__ lhb, const float* __restrict__ lhw,
    const float* __restrict__ luw, const float* __restrict__ lub,
    float* __restrict__ hstate, float* __restrict__ out, int t,
    float* __restrict__ outh)
{
  const int tid = threadIdx.x, lane = tid & 63, w = tid >> 6;
  const int row0 = blockIdx.x * 32;
  const int b = row0 >> 8;
  __shared__ float lhT[HIDD*129];
  __shared__ float rows[4][HIDD];
  __shared__ float otile[HIDD][33];
  __shared__ float qsum[HIDD];
  __shared__ float qqL[HIDD];
  #pragma unroll
  for (int i = 0; i < 64; ++i) {
    int idx = tid + i*256;
    int hp = idx >> 7, k = idx & 127;
    lhT[k*129 + hp] = lhw[idx];
  }
  if (tid < 128) {
    const float* qp = qpartF + (size_t)b*4096;    // 32 partials x 128
    float q = 0.f;
    #pragma unroll 8
    for (int p = 0; p < 32; ++p) q += qp[p*128 + tid];
    qsum[tid] = fmaxf(q + pb[0], 0.f);
  }
  __syncthreads();
  if (tid < 128) {
    float acc = 0.f;
    #pragma unroll 4
    for (int k = 0; k < HIDD; ++k) acc += qsum[k]*lqw[tid*HIDD + k];
    qqL[tid] = acc + lqb[tid] + lhb[tid];
  }
  __syncthreads();
  float qv0 = qqL[lane];
  float qv1 = qqL[64 + lane];
  float lu0 = luw[lane], lu1 = luw[64 + lane];
  float lb = lub[0];
  for (int chunk = 0; chunk < 8; ++chunk) {
    int r0 = row0 + chunk*4;
    #pragma unroll
    for (int i = 0; i < 2; ++i) {
      int idx = tid + i*256;
      rows[idx >> 7][idx & 127] = hmid[(size_t)r0*HIDD + idx];
    }
    __syncthreads();
    const float* R = rows[w];
    float d0 = 0.f, d1 = 0.f;
    #pragma unroll 4
    for (int k = 0; k < HIDD; ++k) {
      float rv = R[k];
      d0 += rv*lhT[k*129 + lane];
      d1 += rv*lhT[k*129 + 64 + lane];
    }
    float t0 = tanhf(d0 + qv0);
    float t1 = tanhf(d1 + qv1);
    float ap = t0*lu0 + t1*lu1;
    #pragma unroll
    for (int off = 32; off > 0; off >>= 1) ap += __shfl_xor(ap, off, 64);
    float a = 1.f/(1.f+expf(-(ap + lb)));
    float o0 = R[lane]     *(1.f+a);
    float o1 = R[64 + lane]*(1.f+a);
    int row = r0 + w, rr = chunk*4 + w;
    hstate[(size_t)row*HIDD + lane]      = o0;
    hstate[(size_t)row*HIDD + 64 + lane] = o1;
    if (outh) {
      outh[(size_t)row*HIDD + lane]      = o0;
      outh[(size_t)row*HIDD + 64 + lane] = o1;
    }
    otile[lane][rr]      = o0;
    otile[64 + lane][rr] = o1;
    __syncthreads();
  }
  #pragma unroll
  for (int i = 0; i < 16; ++i) {
    int idx = tid + i*256;
    int h = idx >> 5, rr = idx & 31;
    out[(size_t)h*(TT*(size_t)BSZ) + (size_t)t*BSZ + row0 + rr] = otile[h][rr];
  }
}

extern "C" void kernel_launch(void* const* d_in, const int* in_sizes, int n_in,
                              void* d_out, int out_size, void* d_ws, size_t ws_size,
                              hipStream_t stream)
{
  const float* x = (const float*)d_in[0];
  GP gp;
  int wIdx[8], aIdx[8], bIdx[4];
  bool dictOrder = (in_sizes[5] == HIDD);
  if (dictOrder) {
    for (int g = 0; g < 4; ++g) {
      int base = 1 + 5*g;
      wIdx[g]   = base;     aIdx[g]   = base + 1;
      wIdx[4+g] = base + 2; aIdx[4+g] = base + 3;
      bIdx[g]   = base + 4;
    }
  } else {
    for (int g = 0; g < 4; ++g) {
      int base = 1 + 4*g;
      wIdx[g]   = base;     aIdx[g]   = base + 1;
      wIdx[4+g] = base + 2; aIdx[4+g] = base + 3;
      bIdx[g]   = 17 + g;
    }
  }
  for (int s = 0; s < 8; ++s) {
    gp.W[s] = (const float*)d_in[wIdx[s]];
    gp.A[s] = (const float*)d_in[aIdx[s]];
  }
  const float* bi  = (const float*)d_in[bIdx[0]];
  const float* bf  = (const float*)d_in[bIdx[1]];
  const float* bc  = (const float*)d_in[bIdx[2]];
  const float* bo  = (const float*)d_in[bIdx[3]];
  const float* pw  = (const float*)d_in[21];
  const float* pb  = (const float*)d_in[22];
  const float* lhw = (const float*)d_in[23];
  const float* lhb = (const float*)d_in[24];
  const float* lqw = (const float*)d_in[25];
  const float* lqb = (const float*)d_in[26];
  const float* luw = (const float*)d_in[27];
  const float* lub = (const float*)d_in[28];

  const size_t S = (size_t)BSZ*HIDD;       // 1048576
  float* ws = (float*)d_ws;
  float* gat    = ws;                      // 8*S floats (32 MB)
  float* hstate = gat + 8*S;               // S
  float* cstate = hstate + S;              // S
  float* hmid   = cstate + S;              // S
  float* f12U   = hmid + S;                // 8*2*BSZ = 131072
  float* qpart  = f12U + 8*2*BSZ;          // 1024*128 = 131072
  float* Wa     = qpart + 131072;          // 2048
  uint4* WfH    = (uint4*)(Wa + 2048);     // 16384 uint4 (256 KB)
  uint4* WfL    = WfH + 8*2048;            // 256 KB
  uint4* HfU    = WfL + 8*2048;            // 8*NB*4096 uint4 = 16 MB
  uint4* HfW    = HfU + (size_t)8*NB*4096;    // 64*NB*4096 uint4 = 128 MB
  float* f12W   = (float*)(HfW + (size_t)64*NB*4096);  // 64*2*BSZ = 4 MB
  // total with prepass ~194 MiB
  bool pre = ws_size >= (size_t)205*1024*1024;

  float* out = (float*)d_out;
  const size_t off = (size_t)HIDD * (size_t)TT * (size_t)BSZ;  // 16777216

  hipMemsetAsync(hstate, 0, S*sizeof(float), stream);
  hipMemsetAsync(cstate, 0, S*sizeof(float), stream);
  k0_convw<<<8, 256, 0, stream>>>(gp, WfH, WfL);
  k0_wa<<<8, 128, 0, stream>>>(gp, Wa);

  if (pre) {
    // all W-side GEMMs for all t in one launch: sy = t*4 + s
    k1_gemm<<<dim3(128, 64), 256, 0, stream>>>(x, hstate, WfH, WfL, Wa,
        HfW, f12W, 0, 3, 2, 1, 0);
  }

  for (int t = 0; t < TT; ++t) {
    bool last = (t == TT - 1);
    if (pre) {
      k1_gemm<<<dim3(128, 4), 256, 0, stream>>>(x, hstate, WfH, WfL, Wa,
          HfU, f12U, 4, 3, 2, 0, t);
      k2_attn<<<dim3(NB, 8, 4), 256, 0, stream>>>(HfW, HfU, f12W, f12U, gat, t, 1);
    } else {
      k1_gemm<<<dim3(128, 8), 256, 0, stream>>>(x, hstate, WfH, WfL, Wa,
          HfU, f12U, 0, 7, 3, 0, t);
      k2_attn<<<dim3(NB, 8, 4), 256, 0, stream>>>(HfU, HfU, f12U, f12U, gat, t, 0);
    }
    k3_gates<<<1024, 256, 0, stream>>>((const float4*)gat, (const float4*)bi,
        (const float4*)bf, (const float4*)bc, (const float4*)bo,
        (float4*)cstate, (float4*)hmid,
        last ? (float4*)(out + off + S) : (float4*)nullptr,
        pw, (float4*)qpart);
    k5_fatt<<<256, 256, 0, stream>>>(hmid, qpart, pb, lqw, lqb, lhb, lhw, luw, lub,
        hstate, out, t, last ? (out + off) : nullptr);
  }
}